// Round 8
// baseline (1163.338 us; speedup 1.0000x reference)
//
#include <hip/hip_runtime.h>
#include <hip/hip_bf16.h>

// GCN: 3x GraphConv(norm='both') + graph readout + dense head.
// Strategy:
//  - ATOMIC-FREE CSR build (R2: device atomics cap ~26G/s):
//      hist (4-bit packed full-range LDS bins, CBITS=16) -> reduce2 (nibble
//      sums + fused norms) -> scan -> fill.
//  - Algebra: transform-first for 128->64 layers so ALL gathers are 64-feat.
//  - bf16 features; 8 lanes/edge uint4 loads (R3); ALL dense multiplies are
//    MFMA 16x16x32 bf16 (R4); gemm2+gemm3 fused via LDS tile (R6).
//  - R7: QUAD-GATHER. One wave = 4 adjacent dst nodes over combined csr
//    range; 128-edge index batches (2 coalesced loads), 16 j-groups -> up to
//    16 scattered loads in flight (2x R6), fixed costs amortized 2x. 3-way
//    boundary routing: uniform single-segment fast path; straddles do only
//    present segments' masked adds.
//  - agg3: block LDS-reduce 32 nodes -> ~1 atomic row/block.

constexpr int NN = 100000;   // nodes
constexpr int NE = 3200000;  // edges
constexpr int NG = 64;       // graphs

constexpr int CBITS = 16;
constexpr int CHUNK = 1 << CBITS;                 // 65536 edges/chunk
constexpr int NCHUNK = (NE + CHUNK - 1) / CHUNK;  // 49
constexpr int WORDS4 = NN / 8;                    // 12500 packed u4x8 words

typedef __attribute__((ext_vector_type(8))) short short8;
typedef __attribute__((ext_vector_type(4))) float f32x4;
typedef __attribute__((ext_vector_type(2))) float f32x2;

// ---------------- chunked LDS histogram (4-bit bins, full node range) -----

__global__ __launch_bounds__(1024) void hist_kernel(
    const int* __restrict__ src, const int* __restrict__ dst,
    uint* __restrict__ pdst, uint* __restrict__ psrc,
    unsigned char* __restrict__ lrank) {
  __shared__ uint bins[WORDS4];  // 50KB
  for (int i = threadIdx.x; i < WORDS4; i += 1024) bins[i] = 0;
  __syncthreads();
  const int c = blockIdx.x;
  const int start = c << CBITS;
  const int end = min(start + CHUNK, NE);
  if (blockIdx.y == 0) {
    for (int i = start + threadIdx.x; i < end; i += 1024) {
      int n = dst[i];
      uint old = atomicAdd(&bins[n >> 3], 1u << ((n & 7) * 4));
      lrank[i] = (unsigned char)((old >> ((n & 7) * 4)) & 0xf);
    }
  } else {
    for (int i = start + threadIdx.x; i < end; i += 1024) {
      int n = src[i];
      atomicAdd(&bins[n >> 3], 1u << ((n & 7) * 4));
    }
  }
  __syncthreads();
  uint* pp = ((blockIdx.y == 0) ? pdst : psrc) + (size_t)c * WORDS4;
  for (int i = threadIdx.x; i < WORDS4; i += 1024) pp[i] = bins[i];
}

// ------- reduce2: nibble sums -> deg_in + chunk-exclusive prefix + norms ---

__global__ __launch_bounds__(256) void reduce2_kernel(
    const uint* __restrict__ pdst, const uint* __restrict__ psrc,
    unsigned char* __restrict__ Pb, int* __restrict__ deg_in,
    float* __restrict__ nd, float* __restrict__ ns) {
  int w = blockIdx.x * 256 + threadIdx.x;
  if (w >= WORDS4) return;
  uint run[8] = {0, 0, 0, 0, 0, 0, 0, 0};
  if (blockIdx.y == 0) {
#pragma unroll 7
    for (int c = 0; c < NCHUNK; ++c) {
      uint lo = run[0] | (run[1] << 8) | (run[2] << 16) | (run[3] << 24);
      uint hi = run[4] | (run[5] << 8) | (run[6] << 16) | (run[7] << 24);
      ((uint2*)(Pb + (size_t)c * NN))[w] = make_uint2(lo, hi);
      uint v = pdst[(size_t)c * WORDS4 + w];
#pragma unroll
      for (int k = 0; k < 8; ++k) run[k] += (v >> (4 * k)) & 0xfu;
    }
    ((int4*)deg_in)[2 * w] = make_int4(run[0], run[1], run[2], run[3]);
    ((int4*)deg_in)[2 * w + 1] = make_int4(run[4], run[5], run[6], run[7]);
    float4 f0, f1;
    f0.x = rsqrtf(fmaxf((float)run[0], 1.f));
    f0.y = rsqrtf(fmaxf((float)run[1], 1.f));
    f0.z = rsqrtf(fmaxf((float)run[2], 1.f));
    f0.w = rsqrtf(fmaxf((float)run[3], 1.f));
    f1.x = rsqrtf(fmaxf((float)run[4], 1.f));
    f1.y = rsqrtf(fmaxf((float)run[5], 1.f));
    f1.z = rsqrtf(fmaxf((float)run[6], 1.f));
    f1.w = rsqrtf(fmaxf((float)run[7], 1.f));
    ((float4*)nd)[2 * w] = f0;
    ((float4*)nd)[2 * w + 1] = f1;
  } else {
#pragma unroll 7
    for (int c = 0; c < NCHUNK; ++c) {
      uint v = psrc[(size_t)c * WORDS4 + w];
#pragma unroll
      for (int k = 0; k < 8; ++k) run[k] += (v >> (4 * k)) & 0xfu;
    }
    float4 f0, f1;
    f0.x = rsqrtf(fmaxf((float)run[0], 1.f));
    f0.y = rsqrtf(fmaxf((float)run[1], 1.f));
    f0.z = rsqrtf(fmaxf((float)run[2], 1.f));
    f0.w = rsqrtf(fmaxf((float)run[3], 1.f));
    f1.x = rsqrtf(fmaxf((float)run[4], 1.f));
    f1.y = rsqrtf(fmaxf((float)run[5], 1.f));
    f1.z = rsqrtf(fmaxf((float)run[6], 1.f));
    f1.w = rsqrtf(fmaxf((float)run[7], 1.f));
    ((float4*)ns)[2 * w] = f0;
    ((float4*)ns)[2 * w + 1] = f1;
  }
}

// ---------------- exclusive scan (1024 elems / block) ----------------

__global__ __launch_bounds__(256) void scan1_kernel(
    const int* __restrict__ deg, int* __restrict__ row_off,
    int* __restrict__ bsums, int n) {
  __shared__ int s[256];
  int t = threadIdx.x;
  int base = blockIdx.x * 1024 + t * 4;
  int v0 = 0, v1 = 0, v2 = 0, v3 = 0;
  if (base + 0 < n) v0 = deg[base + 0];
  if (base + 1 < n) v1 = deg[base + 1];
  if (base + 2 < n) v2 = deg[base + 2];
  if (base + 3 < n) v3 = deg[base + 3];
  int sum = v0 + v1 + v2 + v3;
  s[t] = sum;
  __syncthreads();
  for (int off = 1; off < 256; off <<= 1) {
    int x = (t >= off) ? s[t - off] : 0;
    __syncthreads();
    s[t] += x;
    __syncthreads();
  }
  int excl = s[t] - sum;
  if (t == 255) bsums[blockIdx.x] = s[255];
  if (base + 0 < n) row_off[base + 0] = excl;
  if (base + 1 < n) row_off[base + 1] = excl + v0;
  if (base + 2 < n) row_off[base + 2] = excl + v0 + v1;
  if (base + 3 < n) row_off[base + 3] = excl + v0 + v1 + v2;
}

__global__ __launch_bounds__(128) void scan2_kernel(
    int* __restrict__ bsums, int nb, int* __restrict__ row_off, int n) {
  __shared__ int s[128];
  int t = threadIdx.x;
  int v = (t < nb) ? bsums[t] : 0;
  s[t] = v;
  __syncthreads();
  for (int off = 1; off < 128; off <<= 1) {
    int x = (t >= off) ? s[t - off] : 0;
    __syncthreads();
    s[t] += x;
    __syncthreads();
  }
  if (t < nb) bsums[t] = s[t] - v;
  if (t == 127) row_off[n] = s[127];
}

__global__ __launch_bounds__(256) void scan3_kernel(
    int* __restrict__ row_off, const int* __restrict__ bsums, int n) {
  int i = blockIdx.x * 256 + threadIdx.x;
  if (i < n) row_off[i] += bsums[i >> 10];
}

// ---------------- CSR fill (atomic-free) ----------------

__global__ __launch_bounds__(256) void fill_kernel(
    const int* __restrict__ src, const int* __restrict__ dst,
    const int* __restrict__ row_off, const unsigned char* __restrict__ Pb,
    const unsigned char* __restrict__ lrank, int* __restrict__ csr, int e) {
  int i = blockIdx.x * 256 + threadIdx.x;
  if (i < e) {
    int d = dst[i];
    int c = i >> CBITS;
    int pos = row_off[d] + (int)Pb[(size_t)c * NN + d] + (int)lrank[i];
    csr[pos] = src[i];
  }
}

// ---------------- bf16 helpers ----------------

__device__ __forceinline__ uint pack_bf16(float a, float b) {
  uint ua = __float_as_uint(a), ub = __float_as_uint(b);
  ua = (ua + 0x7fffu + ((ua >> 16) & 1u)) >> 16;          // RNE
  ub = (ub + 0x7fffu + ((ub >> 16) & 1u)) & 0xffff0000u;  // RNE
  return ua | ub;  // a -> low ushort (even idx), b -> high (odd idx)
}

__device__ __forceinline__ ushort to_bf16(float a) {
  uint ua = __float_as_uint(a);
  return (ushort)((ua + 0x7fffu + ((ua >> 16) & 1u)) >> 16);
}

union U16 {
  uint4 u;
  short8 s;
};
__device__ __forceinline__ short8 as_short8(uint4 u) {
  U16 t;
  t.u = u;
  return t.s;
}

__device__ __forceinline__ f32x2 bf2(uint u) {
  f32x2 r;
  r.x = __uint_as_float(u << 16);
  r.y = __uint_as_float(u & 0xffff0000u);
  return r;
}

__device__ __forceinline__ void add8(f32x2* a, uint4 v) {
  a[0] += bf2(v.x);
  a[1] += bf2(v.y);
  a[2] += bf2(v.z);
  a[3] += bf2(v.w);
}

// ---------------- weight transpose + bf16 convert ----------------

__global__ __launch_bounds__(256) void transw_kernel(
    const float* __restrict__ W1, const float* __restrict__ W2,
    const float* __restrict__ W3, ushort* __restrict__ Wt1,
    ushort* __restrict__ Wt2, ushort* __restrict__ Wt3) {
  int i = blockIdx.x * 256 + threadIdx.x;  // 0..24575
  if (i < 8192) {
    int n = i >> 7, k = i & 127;
    Wt1[i] = to_bf16(W1[k * 64 + n]);
  } else if (i < 16384) {
    int j = i - 8192;
    int n = j >> 6, k = j & 63;
    Wt2[j] = to_bf16(W2[k * 128 + n]);
  } else if (i < 24576) {
    int j = i - 16384;
    int n = j >> 7, k = j & 127;
    Wt3[j] = to_bf16(W3[k * 64 + n]);
  }
}

// ---------------- skinny MFMA GEMM (layer 1): t1 = bf16((A@W1)*ns) --------

__global__ __launch_bounds__(256) void gemm1_kernel(
    const float* __restrict__ A, const ushort* __restrict__ Wt,
    const float* __restrict__ scale, ushort* __restrict__ C, int n) {
  int wid = threadIdx.x >> 6, lane = threadIdx.x & 63;
  int r = lane & 15, quad = lane >> 4;
  int m16 = blockIdx.x * 64 + wid * 16;
  if (m16 >= n) return;
  int mc = min(m16 + r, n - 1);
  short8 a[4];
#pragma unroll
  for (int ks = 0; ks < 4; ++ks) {
    const float4* p = (const float4*)(A + (size_t)mc * 128 + ks * 32 + quad * 8);
    float4 x = p[0], y = p[1];
    uint4 u;
    u.x = pack_bf16(x.x, x.y);
    u.y = pack_bf16(x.z, x.w);
    u.z = pack_bf16(y.x, y.y);
    u.w = pack_bf16(y.z, y.w);
    a[ks] = as_short8(u);
  }
#pragma unroll
  for (int nt = 0; nt < 4; ++nt) {
    f32x4 acc = {0.f, 0.f, 0.f, 0.f};
#pragma unroll
    for (int ks = 0; ks < 4; ++ks) {
      short8 b = as_short8(
          *(const uint4*)(Wt + (size_t)(nt * 16 + r) * 128 + ks * 32 + quad * 8));
      acc = __builtin_amdgcn_mfma_f32_16x16x32_bf16(a[ks], b, acc, 0, 0, 0);
    }
#pragma unroll
    for (int reg = 0; reg < 4; ++reg) {
      int m = m16 + quad * 4 + reg;
      if (m < n) C[(size_t)m * 64 + nt * 16 + r] = to_bf16(acc[reg] * scale[m]);
    }
  }
}

// ------- fused layers 2+3 dense: t3 = (relu(m2@W2+b2)*ns) @ W3 ------------

__global__ __launch_bounds__(256) void gemm23_kernel(
    const ushort* __restrict__ m2, const ushort* __restrict__ Wt2,
    const float* __restrict__ b2, const float* __restrict__ ns,
    const ushort* __restrict__ Wt3, ushort* __restrict__ t3, int n) {
  __shared__ ushort sX[4][16][136];  // 17.4KB, pad keeps 16B align
  int wid = threadIdx.x >> 6, lane = threadIdx.x & 63;
  int r = lane & 15, quad = lane >> 4;
  int m16 = blockIdx.x * 64 + wid * 16;
  if (m16 >= n) return;
  int mc = min(m16 + r, n - 1);
  short8 a1[2];
#pragma unroll
  for (int ks = 0; ks < 2; ++ks)
    a1[ks] = as_short8(*(const uint4*)(m2 + (size_t)mc * 64 + ks * 32 + quad * 8));
  float nsv[4];
#pragma unroll
  for (int reg = 0; reg < 4; ++reg)
    nsv[reg] = ns[min(m16 + quad * 4 + reg, n - 1)];
#pragma unroll
  for (int nt = 0; nt < 8; ++nt) {
    f32x4 acc = {0.f, 0.f, 0.f, 0.f};
#pragma unroll
    for (int ks = 0; ks < 2; ++ks) {
      short8 b = as_short8(
          *(const uint4*)(Wt2 + (size_t)(nt * 16 + r) * 64 + ks * 32 + quad * 8));
      acc = __builtin_amdgcn_mfma_f32_16x16x32_bf16(a1[ks], b, acc, 0, 0, 0);
    }
    float bv = b2[nt * 16 + r];
#pragma unroll
    for (int reg = 0; reg < 4; ++reg) {
      float v = fmaxf(acc[reg] + bv, 0.f) * nsv[reg];
      sX[wid][quad * 4 + reg][nt * 16 + r] = to_bf16(v);
    }
  }
  short8 a2[4];
#pragma unroll
  for (int ks = 0; ks < 4; ++ks)
    a2[ks] = as_short8(*(const uint4*)(&sX[wid][r][ks * 32 + quad * 8]));
#pragma unroll
  for (int nt = 0; nt < 4; ++nt) {
    f32x4 acc = {0.f, 0.f, 0.f, 0.f};
#pragma unroll
    for (int ks = 0; ks < 4; ++ks) {
      short8 b = as_short8(
          *(const uint4*)(Wt3 + (size_t)(nt * 16 + r) * 128 + ks * 32 + quad * 8));
      acc = __builtin_amdgcn_mfma_f32_16x16x32_bf16(a2[ks], b, acc, 0, 0, 0);
    }
#pragma unroll
    for (int reg = 0; reg < 4; ++reg) {
      int m = m16 + quad * 4 + reg;
      if (m < n) t3[(size_t)m * 64 + nt * 16 + r] = to_bf16(acc[reg]);
    }
  }
}

// ---------------- quad 64-feature bf16 CSR gather ----------------
// One wave gathers FOUR adjacent dst rows over the combined contiguous csr
// range [rs, re), boundaries rm1<rm2<rm3. 128-edge index batches (2 coalesced
// loads), 16 j-groups of 8 edges each -> up to 16 scattered uint4 loads in
// flight. Wave-uniform single-segment fast path; straddles do only the
// present segments' masked adds. Butterfly leaves all 4 nodes' totals.

__device__ __forceinline__ void add8_seg(f32x2* a0, f32x2* a1, f32x2* a2,
                                         f32x2* a3, int t, uint4 v) {
  switch (t) {
    case 0: add8(a0, v); break;
    case 1: add8(a1, v); break;
    case 2: add8(a2, v); break;
    default: add8(a3, v); break;
  }
}

__device__ __forceinline__ void bfly8(f32x2* a) {
#pragma unroll
  for (int k = 0; k < 4; ++k) {
    a[k].x += __shfl_xor(a[k].x, 8);
    a[k].x += __shfl_xor(a[k].x, 16);
    a[k].x += __shfl_xor(a[k].x, 32);
    a[k].y += __shfl_xor(a[k].y, 8);
    a[k].y += __shfl_xor(a[k].y, 16);
    a[k].y += __shfl_xor(a[k].y, 32);
  }
}

__device__ __forceinline__ void gather4_bf16(const int* __restrict__ csr,
                                             const ushort* __restrict__ x,
                                             int rs, int rm1, int rm2, int rm3,
                                             int re, int lane, f32x2* a0,
                                             f32x2* a1, f32x2* a2, f32x2* a3) {
  const int eg = lane >> 3;
  const int fl = lane & 7;
  for (int e0 = rs; e0 < re; e0 += 128) {
    int i1 = e0 + lane, i2 = e0 + 64 + lane;
    int sv0 = (i1 < re) ? csr[i1] : 0;
    int sv1 = (i2 < re) ? csr[i2] : 0;
    int cnt = re - e0;
    if (cnt > 128) cnt = 128;
    int c1 = rm1 - e0, c2 = rm2 - e0, c3 = rm3 - e0;
#pragma unroll
    for (int j = 0; j < 16; ++j) {
      int jb = j * 8;
      if (jb < cnt) {  // wave-uniform
        int s = __shfl((j < 8) ? sv0 : sv1, (jb & 63) + eg);
        uint4 v = *(const uint4*)(x + (size_t)s * 64 + fl * 8);
        if (jb + 8 > cnt) {  // partial tail: zero invalid edge-groups
          uint mv = ((jb + eg) < cnt) ? 0xffffffffu : 0u;
          v.x &= mv; v.y &= mv; v.z &= mv; v.w &= mv;
        }
        int slo = (jb >= c1) + (jb >= c2) + (jb >= c3);
        int shi = (jb + 7 >= c1) + (jb + 7 >= c2) + (jb + 7 >= c3);
        if (slo == shi) {
          add8_seg(a0, a1, a2, a3, slo, v);
        } else {  // straddle: only segments [slo..shi] present
          int p = jb + eg;
          int sp = (p >= c1) + (p >= c2) + (p >= c3);
#pragma unroll
          for (int t = 0; t < 4; ++t) {
            if (t >= slo && t <= shi) {  // wave-uniform
              uint m = (sp == t) ? 0xffffffffu : 0u;
              uint4 vm;
              vm.x = v.x & m; vm.y = v.y & m; vm.z = v.z & m; vm.w = v.w & m;
              add8_seg(a0, a1, a2, a3, t, vm);
            }
          }
        }
      }
    }
  }
  bfly8(a0);
  bfly8(a1);
  bfly8(a2);
  bfly8(a3);
}

// select feature k (0..7) of node eg's accumulator (eg in 0..3)
#define ASEL(k)                                            \
  ((eg == 0)   ? a0[(k) >> 1][(k)&1]                       \
   : (eg == 1) ? a1[(k) >> 1][(k)&1]                       \
   : (eg == 2) ? a2[(k) >> 1][(k)&1]                       \
               : a3[(k) >> 1][(k)&1])

// ---------------- layer 1 aggregate + epilogue (bf16 out) ----------------
// h1s[n][j] = bf16(relu(seg(t1)*nd + b1[j]) * ns[n]); 4 nodes/wave.

__global__ __launch_bounds__(256) void agg1_kernel(
    const int* __restrict__ row_off, const int* __restrict__ csr,
    const ushort* __restrict__ t, const float* __restrict__ nd,
    const float* __restrict__ ns, const float* __restrict__ b,
    ushort* __restrict__ out, int n) {
  int wid = threadIdx.x >> 6, lane = threadIdx.x & 63;
  int n0 = blockIdx.x * 16 + wid * 4;  // n % 16 == 0
  int rs = row_off[n0], rm1 = row_off[n0 + 1], rm2 = row_off[n0 + 2],
      rm3 = row_off[n0 + 3], re = row_off[n0 + 4];
  f32x2 a0[4] = {{0, 0}, {0, 0}, {0, 0}, {0, 0}};
  f32x2 a1[4] = {{0, 0}, {0, 0}, {0, 0}, {0, 0}};
  f32x2 a2[4] = {{0, 0}, {0, 0}, {0, 0}, {0, 0}};
  f32x2 a3[4] = {{0, 0}, {0, 0}, {0, 0}, {0, 0}};
  gather4_bf16(csr, t, rs, rm1, rm2, rm3, re, lane, a0, a1, a2, a3);
  int eg = lane >> 3, fl = lane & 7;
  if (eg < 4) {
    int node = n0 + eg;
    float ndv = nd[node], nsv = ns[node];
    const float4* bp = (const float4*)(b + fl * 8);
    float4 b0 = bp[0], b1v = bp[1];
    float o0 = fmaxf(ASEL(0) * ndv + b0.x, 0.f) * nsv;
    float o1 = fmaxf(ASEL(1) * ndv + b0.y, 0.f) * nsv;
    float o2 = fmaxf(ASEL(2) * ndv + b0.z, 0.f) * nsv;
    float o3 = fmaxf(ASEL(3) * ndv + b0.w, 0.f) * nsv;
    float o4 = fmaxf(ASEL(4) * ndv + b1v.x, 0.f) * nsv;
    float o5 = fmaxf(ASEL(5) * ndv + b1v.y, 0.f) * nsv;
    float o6 = fmaxf(ASEL(6) * ndv + b1v.z, 0.f) * nsv;
    float o7 = fmaxf(ASEL(7) * ndv + b1v.w, 0.f) * nsv;
    uint4 v;
    v.x = pack_bf16(o0, o1);
    v.y = pack_bf16(o2, o3);
    v.z = pack_bf16(o4, o5);
    v.w = pack_bf16(o6, o7);
    *(uint4*)(out + (size_t)node * 64 + fl * 8) = v;
  }
}

// ---------------- layer 2 aggregate (gather-only, bf16 out) ----------------

__global__ __launch_bounds__(256) void agg2_kernel(
    const int* __restrict__ row_off, const int* __restrict__ csr,
    const ushort* __restrict__ h1s, const float* __restrict__ nd,
    ushort* __restrict__ m2, int n) {
  int wid = threadIdx.x >> 6, lane = threadIdx.x & 63;
  int n0 = blockIdx.x * 16 + wid * 4;
  int rs = row_off[n0], rm1 = row_off[n0 + 1], rm2 = row_off[n0 + 2],
      rm3 = row_off[n0 + 3], re = row_off[n0 + 4];
  f32x2 a0[4] = {{0, 0}, {0, 0}, {0, 0}, {0, 0}};
  f32x2 a1[4] = {{0, 0}, {0, 0}, {0, 0}, {0, 0}};
  f32x2 a2[4] = {{0, 0}, {0, 0}, {0, 0}, {0, 0}};
  f32x2 a3[4] = {{0, 0}, {0, 0}, {0, 0}, {0, 0}};
  gather4_bf16(csr, h1s, rs, rm1, rm2, rm3, re, lane, a0, a1, a2, a3);
  int eg = lane >> 3, fl = lane & 7;
  if (eg < 4) {
    int node = n0 + eg;
    float ndv = nd[node];
    uint4 v;
    v.x = pack_bf16(ASEL(0) * ndv, ASEL(1) * ndv);
    v.y = pack_bf16(ASEL(2) * ndv, ASEL(3) * ndv);
    v.z = pack_bf16(ASEL(4) * ndv, ASEL(5) * ndv);
    v.w = pack_bf16(ASEL(6) * ndv, ASEL(7) * ndv);
    *(uint4*)(m2 + (size_t)node * 64 + fl * 8) = v;
  }
}

// ---------------- layer 3 aggregate + block-reduced readout ----------------
// 512 threads = 8 waves x 4 nodes = 32 nodes/block; LDS tree-reduce ->
// ~1 atomic row per block (gids sorted: ~98% of blocks gid-uniform).

__global__ __launch_bounds__(512) void agg3_kernel(
    const int* __restrict__ row_off, const int* __restrict__ csr,
    const ushort* __restrict__ t, const float* __restrict__ nd,
    const float* __restrict__ b, const int* __restrict__ gid,
    float* __restrict__ hg, int n) {
  __shared__ float sO[32][64];
  __shared__ int sG[32];
  __shared__ int uni;
  int wid = threadIdx.x >> 6, lane = threadIdx.x & 63;
  int n0 = blockIdx.x * 32 + wid * 4;  // NN % 32 == 0
  int rs = row_off[n0], rm1 = row_off[n0 + 1], rm2 = row_off[n0 + 2],
      rm3 = row_off[n0 + 3], re = row_off[n0 + 4];
  f32x2 a0[4] = {{0, 0}, {0, 0}, {0, 0}, {0, 0}};
  f32x2 a1[4] = {{0, 0}, {0, 0}, {0, 0}, {0, 0}};
  f32x2 a2[4] = {{0, 0}, {0, 0}, {0, 0}, {0, 0}};
  f32x2 a3[4] = {{0, 0}, {0, 0}, {0, 0}, {0, 0}};
  gather4_bf16(csr, t, rs, rm1, rm2, rm3, re, lane, a0, a1, a2, a3);
  int eg = lane >> 3, fl = lane & 7;
  if (eg < 4) {
    int node = n0 + eg;
    int row = wid * 4 + eg;
    float ndv = nd[node];
    const float4* bp = (const float4*)(b + fl * 8);
    float4 b0 = bp[0], b1v = bp[1];
    sO[row][fl * 8 + 0] = fmaxf(ASEL(0) * ndv + b0.x, 0.f);
    sO[row][fl * 8 + 1] = fmaxf(ASEL(1) * ndv + b0.y, 0.f);
    sO[row][fl * 8 + 2] = fmaxf(ASEL(2) * ndv + b0.z, 0.f);
    sO[row][fl * 8 + 3] = fmaxf(ASEL(3) * ndv + b0.w, 0.f);
    sO[row][fl * 8 + 4] = fmaxf(ASEL(4) * ndv + b1v.x, 0.f);
    sO[row][fl * 8 + 5] = fmaxf(ASEL(5) * ndv + b1v.y, 0.f);
    sO[row][fl * 8 + 6] = fmaxf(ASEL(6) * ndv + b1v.z, 0.f);
    sO[row][fl * 8 + 7] = fmaxf(ASEL(7) * ndv + b1v.w, 0.f);
    if (fl == 0) sG[row] = gid[node];
  }
  __syncthreads();
  if (threadIdx.x == 0) {
    int g0 = sG[0], u = 1;
#pragma unroll
    for (int i = 1; i < 32; ++i) u &= (sG[i] == g0);
    uni = u;
  }
  __syncthreads();
  if (uni) {
    int r = threadIdx.x >> 6;  // 0..7
#pragma unroll
    for (int s = 16; s >= 1; s >>= 1) {
      for (int rr = r; rr < s; rr += 8) sO[rr][lane] += sO[rr + s][lane];
      __syncthreads();
    }
    if (threadIdx.x < 64) atomicAdd(&hg[sG[0] * 64 + lane], sO[0][lane]);
  } else {
#pragma unroll
    for (int i = 0; i < 4; ++i) {
      int row = wid * 4 + i;
      atomicAdd(&hg[sG[row] * 64 + lane], sO[row][lane]);
    }
  }
}

// ---------------- readout dense ----------------

__global__ __launch_bounds__(640) void readout_kernel(
    const float* __restrict__ hg, const float* __restrict__ Wd,
    const float* __restrict__ bd, float* __restrict__ out) {
  int t = threadIdx.x;  // 640 = 64 graphs * 10 classes
  int g = t / 10, c = t % 10;
  float o = bd[c];
#pragma unroll 8
  for (int k = 0; k < 64; ++k) o += tanhf(hg[g * 64 + k]) * Wd[k * 10 + c];
  out[t] = o;
}

// ---------------- launch ----------------

extern "C" void kernel_launch(void* const* d_in, const int* in_sizes, int n_in,
                              void* d_out, int out_size, void* d_ws, size_t ws_size,
                              hipStream_t stream) {
  const float* in_feat = (const float*)d_in[0];
  const int* src = (const int*)d_in[1];
  const int* dst = (const int*)d_in[2];
  const int* gid = (const int*)d_in[3];
  const float* W1 = (const float*)d_in[4];
  const float* b1 = (const float*)d_in[5];
  const float* W2 = (const float*)d_in[6];
  const float* b2 = (const float*)d_in[7];
  const float* W3 = (const float*)d_in[8];
  const float* b3 = (const float*)d_in[9];
  const float* Wd = (const float*)d_in[10];
  const float* bd = (const float*)d_in[11];
  float* out = (float*)d_out;

  char* ws = (char*)d_ws;
  size_t o = 0;
  auto alloc = [&](size_t bytes) -> char* {
    char* p = ws + o;
    o = (o + bytes + 1023) & ~(size_t)1023;
    return p;
  };
  float* hg = (float*)alloc(NG * 64 * 4);
  size_t zero_bytes = o;  // only hg needs zero-init
  int* deg_in = (int*)alloc(NN * 4);
  float* norm_src = (float*)alloc(NN * 4);
  float* norm_dst = (float*)alloc(NN * 4);
  int* row_off = (int*)alloc((NN + 1) * 4);
  int* bsums = (int*)alloc(512);
  ushort* Wt1 = (ushort*)alloc(64 * 128 * 2);
  ushort* Wt2 = (ushort*)alloc(128 * 64 * 2);
  ushort* Wt3 = (ushort*)alloc(64 * 128 * 2);
  int* csr = (int*)alloc((size_t)NE * 4);
  ushort* tbuf = (ushort*)alloc((size_t)NN * 64 * 2);  // bf16 t1, then t3
  ushort* h1s = (ushort*)alloc((size_t)NN * 64 * 2);   // bf16
  ushort* m2 = (ushort*)alloc((size_t)NN * 64 * 2);    // bf16
  (void)ws_size;

  // overlays on [tbuf..) (38.4MB contiguous): all CSR-build scratch is dead
  // before gemm1 (tbuf), agg1 (h1s), agg2 (m2) first write.
  char* ov = (char*)tbuf;
  uint* pdst = (uint*)ov;                                 // 2.45MB
  uint* psrc = (uint*)(ov + 2457600);                     // 2.45MB
  unsigned char* Pb = (unsigned char*)(ov + 4915200);     // 4.9MB
  unsigned char* lrank = (unsigned char*)(ov + 9830400);  // 3.2MB

  hipMemsetAsync(d_ws, 0, zero_bytes, stream);

  const int egrid = (NE + 255) / 256;      // 12500
  const int ngrid = (NN + 255) / 256;      // 391
  const int sgrid = (NN + 1023) / 1024;    // 98
  const int qgrid = NN / 16;               // 6250 (quad-gather, 4 waves/blk)
  const int rgrid = (WORDS4 + 255) / 256;  // 49
  const int ggrid = (NN + 63) / 64;        // 1563

  transw_kernel<<<96, 256, 0, stream>>>(W1, W2, W3, Wt1, Wt2, Wt3);
  hist_kernel<<<dim3(NCHUNK, 2), 1024, 0, stream>>>(src, dst, pdst, psrc, lrank);
  reduce2_kernel<<<dim3(rgrid, 2), 256, 0, stream>>>(pdst, psrc, Pb, deg_in,
                                                     norm_dst, norm_src);
  scan1_kernel<<<sgrid, 256, 0, stream>>>(deg_in, row_off, bsums, NN);
  scan2_kernel<<<1, 128, 0, stream>>>(bsums, sgrid, row_off, NN);
  scan3_kernel<<<ngrid, 256, 0, stream>>>(row_off, bsums, NN);
  fill_kernel<<<egrid, 256, 0, stream>>>(src, dst, row_off, Pb, lrank, csr, NE);

  // layer 1: t1 = bf16((in_feat @ W1) * ns)   [MFMA]
  gemm1_kernel<<<ggrid, 256, 0, stream>>>(in_feat, Wt1, norm_src, tbuf, NN);
  // h1s = bf16(relu(seg(t1)*nd + b1) * ns)
  agg1_kernel<<<qgrid, 256, 0, stream>>>(row_off, csr, tbuf, norm_dst,
                                         norm_src, b1, h1s, NN);
  // m2 = bf16(seg(h1s)*nd)
  agg2_kernel<<<qgrid, 256, 0, stream>>>(row_off, csr, h1s, norm_dst, m2, NN);
  // t3 = bf16((relu(m2@W2+b2)*ns) @ W3)   [fused MFMA x2]
  gemm23_kernel<<<ggrid, 256, 0, stream>>>(m2, Wt2, b2, norm_src, Wt3, tbuf, NN);
  // hg[g] += relu(seg(t3)*nd + b3)
  agg3_kernel<<<NN / 32, 512, 0, stream>>>(row_off, csr, tbuf, norm_dst, b3,
                                           gid, hg, NN);
  readout_kernel<<<1, 640, 0, stream>>>(hg, Wd, bd, out);
}

// Round 9
// 510.361 us; speedup vs baseline: 2.2794x; 2.2794x over previous
//
#include <hip/hip_runtime.h>
#include <hip/hip_bf16.h>

// GCN: 3x GraphConv(norm='both') + graph readout + dense head.
// Strategy:
//  - ATOMIC-FREE CSR build (R2: device atomics cap ~26G/s):
//      hist (4-bit packed full-range LDS bins, CBITS=16) -> reduce2 (nibble
//      sums + fused norms) -> scan -> fill.
//  - Algebra: transform-first for 128->64 layers so ALL gathers are 64-feat.
//  - bf16 features; 8 lanes/edge uint4 loads (R3); ALL dense multiplies are
//    MFMA 16x16x32 bf16 (R4); gemm2+gemm3 fused via LDS tile (R6).
//  - R7/R8: QUAD-GATHER (4 adjacent dst nodes/wave, 128-edge index batches,
//    16 j-groups in flight). R8 REGRESSED 2.5x: runtime-indexed private
//    accumulator arrays (add8_seg switch + ASEL array ternaries) were merged
//    into a dynamically-indexed alloca -> scratch demotion (agg1 WRITE 465MB,
//    VALU 1.6%). R9 fix: 16 NAMED f32x2 accumulators, compile-time-only
//    accumulator identity (uniform if/else + value ternaries). No arrays.
//  - agg3: block LDS-reduce 32 nodes -> ~1 atomic row/block.

constexpr int NN = 100000;   // nodes
constexpr int NE = 3200000;  // edges
constexpr int NG = 64;       // graphs

constexpr int CBITS = 16;
constexpr int CHUNK = 1 << CBITS;                 // 65536 edges/chunk
constexpr int NCHUNK = (NE + CHUNK - 1) / CHUNK;  // 49
constexpr int WORDS4 = NN / 8;                    // 12500 packed u4x8 words

typedef __attribute__((ext_vector_type(8))) short short8;
typedef __attribute__((ext_vector_type(4))) float f32x4;
typedef __attribute__((ext_vector_type(2))) float f32x2;

// ---------------- chunked LDS histogram (4-bit bins, full node range) -----

__global__ __launch_bounds__(1024) void hist_kernel(
    const int* __restrict__ src, const int* __restrict__ dst,
    uint* __restrict__ pdst, uint* __restrict__ psrc,
    unsigned char* __restrict__ lrank) {
  __shared__ uint bins[WORDS4];  // 50KB
  for (int i = threadIdx.x; i < WORDS4; i += 1024) bins[i] = 0;
  __syncthreads();
  const int c = blockIdx.x;
  const int start = c << CBITS;
  const int end = min(start + CHUNK, NE);
  if (blockIdx.y == 0) {
    for (int i = start + threadIdx.x; i < end; i += 1024) {
      int n = dst[i];
      uint old = atomicAdd(&bins[n >> 3], 1u << ((n & 7) * 4));
      lrank[i] = (unsigned char)((old >> ((n & 7) * 4)) & 0xf);
    }
  } else {
    for (int i = start + threadIdx.x; i < end; i += 1024) {
      int n = src[i];
      atomicAdd(&bins[n >> 3], 1u << ((n & 7) * 4));
    }
  }
  __syncthreads();
  uint* pp = ((blockIdx.y == 0) ? pdst : psrc) + (size_t)c * WORDS4;
  for (int i = threadIdx.x; i < WORDS4; i += 1024) pp[i] = bins[i];
}

// ------- reduce2: nibble sums -> deg_in + chunk-exclusive prefix + norms ---

__global__ __launch_bounds__(256) void reduce2_kernel(
    const uint* __restrict__ pdst, const uint* __restrict__ psrc,
    unsigned char* __restrict__ Pb, int* __restrict__ deg_in,
    float* __restrict__ nd, float* __restrict__ ns) {
  int w = blockIdx.x * 256 + threadIdx.x;
  if (w >= WORDS4) return;
  uint run[8] = {0, 0, 0, 0, 0, 0, 0, 0};
  if (blockIdx.y == 0) {
#pragma unroll 7
    for (int c = 0; c < NCHUNK; ++c) {
      uint lo = run[0] | (run[1] << 8) | (run[2] << 16) | (run[3] << 24);
      uint hi = run[4] | (run[5] << 8) | (run[6] << 16) | (run[7] << 24);
      ((uint2*)(Pb + (size_t)c * NN))[w] = make_uint2(lo, hi);
      uint v = pdst[(size_t)c * WORDS4 + w];
#pragma unroll
      for (int k = 0; k < 8; ++k) run[k] += (v >> (4 * k)) & 0xfu;
    }
    ((int4*)deg_in)[2 * w] = make_int4(run[0], run[1], run[2], run[3]);
    ((int4*)deg_in)[2 * w + 1] = make_int4(run[4], run[5], run[6], run[7]);
    float4 f0, f1;
    f0.x = rsqrtf(fmaxf((float)run[0], 1.f));
    f0.y = rsqrtf(fmaxf((float)run[1], 1.f));
    f0.z = rsqrtf(fmaxf((float)run[2], 1.f));
    f0.w = rsqrtf(fmaxf((float)run[3], 1.f));
    f1.x = rsqrtf(fmaxf((float)run[4], 1.f));
    f1.y = rsqrtf(fmaxf((float)run[5], 1.f));
    f1.z = rsqrtf(fmaxf((float)run[6], 1.f));
    f1.w = rsqrtf(fmaxf((float)run[7], 1.f));
    ((float4*)nd)[2 * w] = f0;
    ((float4*)nd)[2 * w + 1] = f1;
  } else {
#pragma unroll 7
    for (int c = 0; c < NCHUNK; ++c) {
      uint v = psrc[(size_t)c * WORDS4 + w];
#pragma unroll
      for (int k = 0; k < 8; ++k) run[k] += (v >> (4 * k)) & 0xfu;
    }
    float4 f0, f1;
    f0.x = rsqrtf(fmaxf((float)run[0], 1.f));
    f0.y = rsqrtf(fmaxf((float)run[1], 1.f));
    f0.z = rsqrtf(fmaxf((float)run[2], 1.f));
    f0.w = rsqrtf(fmaxf((float)run[3], 1.f));
    f1.x = rsqrtf(fmaxf((float)run[4], 1.f));
    f1.y = rsqrtf(fmaxf((float)run[5], 1.f));
    f1.z = rsqrtf(fmaxf((float)run[6], 1.f));
    f1.w = rsqrtf(fmaxf((float)run[7], 1.f));
    ((float4*)ns)[2 * w] = f0;
    ((float4*)ns)[2 * w + 1] = f1;
  }
}

// ---------------- exclusive scan (1024 elems / block) ----------------

__global__ __launch_bounds__(256) void scan1_kernel(
    const int* __restrict__ deg, int* __restrict__ row_off,
    int* __restrict__ bsums, int n) {
  __shared__ int s[256];
  int t = threadIdx.x;
  int base = blockIdx.x * 1024 + t * 4;
  int v0 = 0, v1 = 0, v2 = 0, v3 = 0;
  if (base + 0 < n) v0 = deg[base + 0];
  if (base + 1 < n) v1 = deg[base + 1];
  if (base + 2 < n) v2 = deg[base + 2];
  if (base + 3 < n) v3 = deg[base + 3];
  int sum = v0 + v1 + v2 + v3;
  s[t] = sum;
  __syncthreads();
  for (int off = 1; off < 256; off <<= 1) {
    int x = (t >= off) ? s[t - off] : 0;
    __syncthreads();
    s[t] += x;
    __syncthreads();
  }
  int excl = s[t] - sum;
  if (t == 255) bsums[blockIdx.x] = s[255];
  if (base + 0 < n) row_off[base + 0] = excl;
  if (base + 1 < n) row_off[base + 1] = excl + v0;
  if (base + 2 < n) row_off[base + 2] = excl + v0 + v1;
  if (base + 3 < n) row_off[base + 3] = excl + v0 + v1 + v2;
}

__global__ __launch_bounds__(128) void scan2_kernel(
    int* __restrict__ bsums, int nb, int* __restrict__ row_off, int n) {
  __shared__ int s[128];
  int t = threadIdx.x;
  int v = (t < nb) ? bsums[t] : 0;
  s[t] = v;
  __syncthreads();
  for (int off = 1; off < 128; off <<= 1) {
    int x = (t >= off) ? s[t - off] : 0;
    __syncthreads();
    s[t] += x;
    __syncthreads();
  }
  if (t < nb) bsums[t] = s[t] - v;
  if (t == 127) row_off[n] = s[127];
}

__global__ __launch_bounds__(256) void scan3_kernel(
    int* __restrict__ row_off, const int* __restrict__ bsums, int n) {
  int i = blockIdx.x * 256 + threadIdx.x;
  if (i < n) row_off[i] += bsums[i >> 10];
}

// ---------------- CSR fill (atomic-free) ----------------

__global__ __launch_bounds__(256) void fill_kernel(
    const int* __restrict__ src, const int* __restrict__ dst,
    const int* __restrict__ row_off, const unsigned char* __restrict__ Pb,
    const unsigned char* __restrict__ lrank, int* __restrict__ csr, int e) {
  int i = blockIdx.x * 256 + threadIdx.x;
  if (i < e) {
    int d = dst[i];
    int c = i >> CBITS;
    int pos = row_off[d] + (int)Pb[(size_t)c * NN + d] + (int)lrank[i];
    csr[pos] = src[i];
  }
}

// ---------------- bf16 helpers ----------------

__device__ __forceinline__ uint pack_bf16(float a, float b) {
  uint ua = __float_as_uint(a), ub = __float_as_uint(b);
  ua = (ua + 0x7fffu + ((ua >> 16) & 1u)) >> 16;          // RNE
  ub = (ub + 0x7fffu + ((ub >> 16) & 1u)) & 0xffff0000u;  // RNE
  return ua | ub;  // a -> low ushort (even idx), b -> high (odd idx)
}

__device__ __forceinline__ ushort to_bf16(float a) {
  uint ua = __float_as_uint(a);
  return (ushort)((ua + 0x7fffu + ((ua >> 16) & 1u)) >> 16);
}

union U16 {
  uint4 u;
  short8 s;
};
__device__ __forceinline__ short8 as_short8(uint4 u) {
  U16 t;
  t.u = u;
  return t.s;
}

__device__ __forceinline__ f32x2 bf2(uint u) {
  f32x2 r;
  r.x = __uint_as_float(u << 16);
  r.y = __uint_as_float(u & 0xffff0000u);
  return r;
}

// ---------------- weight transpose + bf16 convert ----------------

__global__ __launch_bounds__(256) void transw_kernel(
    const float* __restrict__ W1, const float* __restrict__ W2,
    const float* __restrict__ W3, ushort* __restrict__ Wt1,
    ushort* __restrict__ Wt2, ushort* __restrict__ Wt3) {
  int i = blockIdx.x * 256 + threadIdx.x;  // 0..24575
  if (i < 8192) {
    int n = i >> 7, k = i & 127;
    Wt1[i] = to_bf16(W1[k * 64 + n]);
  } else if (i < 16384) {
    int j = i - 8192;
    int n = j >> 6, k = j & 63;
    Wt2[j] = to_bf16(W2[k * 128 + n]);
  } else if (i < 24576) {
    int j = i - 16384;
    int n = j >> 7, k = j & 127;
    Wt3[j] = to_bf16(W3[k * 64 + n]);
  }
}

// ---------------- skinny MFMA GEMM (layer 1): t1 = bf16((A@W1)*ns) --------

__global__ __launch_bounds__(256) void gemm1_kernel(
    const float* __restrict__ A, const ushort* __restrict__ Wt,
    const float* __restrict__ scale, ushort* __restrict__ C, int n) {
  int wid = threadIdx.x >> 6, lane = threadIdx.x & 63;
  int r = lane & 15, quad = lane >> 4;
  int m16 = blockIdx.x * 64 + wid * 16;
  if (m16 >= n) return;
  int mc = min(m16 + r, n - 1);
  short8 a[4];
#pragma unroll
  for (int ks = 0; ks < 4; ++ks) {
    const float4* p = (const float4*)(A + (size_t)mc * 128 + ks * 32 + quad * 8);
    float4 x = p[0], y = p[1];
    uint4 u;
    u.x = pack_bf16(x.x, x.y);
    u.y = pack_bf16(x.z, x.w);
    u.z = pack_bf16(y.x, y.y);
    u.w = pack_bf16(y.z, y.w);
    a[ks] = as_short8(u);
  }
#pragma unroll
  for (int nt = 0; nt < 4; ++nt) {
    f32x4 acc = {0.f, 0.f, 0.f, 0.f};
#pragma unroll
    for (int ks = 0; ks < 4; ++ks) {
      short8 b = as_short8(
          *(const uint4*)(Wt + (size_t)(nt * 16 + r) * 128 + ks * 32 + quad * 8));
      acc = __builtin_amdgcn_mfma_f32_16x16x32_bf16(a[ks], b, acc, 0, 0, 0);
    }
#pragma unroll
    for (int reg = 0; reg < 4; ++reg) {
      int m = m16 + quad * 4 + reg;
      if (m < n) C[(size_t)m * 64 + nt * 16 + r] = to_bf16(acc[reg] * scale[m]);
    }
  }
}

// ------- fused layers 2+3 dense: t3 = (relu(m2@W2+b2)*ns) @ W3 ------------

__global__ __launch_bounds__(256) void gemm23_kernel(
    const ushort* __restrict__ m2, const ushort* __restrict__ Wt2,
    const float* __restrict__ b2, const float* __restrict__ ns,
    const ushort* __restrict__ Wt3, ushort* __restrict__ t3, int n) {
  __shared__ ushort sX[4][16][136];  // 17.4KB, pad keeps 16B align
  int wid = threadIdx.x >> 6, lane = threadIdx.x & 63;
  int r = lane & 15, quad = lane >> 4;
  int m16 = blockIdx.x * 64 + wid * 16;
  if (m16 >= n) return;
  int mc = min(m16 + r, n - 1);
  short8 a1[2];
#pragma unroll
  for (int ks = 0; ks < 2; ++ks)
    a1[ks] = as_short8(*(const uint4*)(m2 + (size_t)mc * 64 + ks * 32 + quad * 8));
  float nsv[4];
#pragma unroll
  for (int reg = 0; reg < 4; ++reg)
    nsv[reg] = ns[min(m16 + quad * 4 + reg, n - 1)];
#pragma unroll
  for (int nt = 0; nt < 8; ++nt) {
    f32x4 acc = {0.f, 0.f, 0.f, 0.f};
#pragma unroll
    for (int ks = 0; ks < 2; ++ks) {
      short8 b = as_short8(
          *(const uint4*)(Wt2 + (size_t)(nt * 16 + r) * 64 + ks * 32 + quad * 8));
      acc = __builtin_amdgcn_mfma_f32_16x16x32_bf16(a1[ks], b, acc, 0, 0, 0);
    }
    float bv = b2[nt * 16 + r];
#pragma unroll
    for (int reg = 0; reg < 4; ++reg) {
      float v = fmaxf(acc[reg] + bv, 0.f) * nsv[reg];
      sX[wid][quad * 4 + reg][nt * 16 + r] = to_bf16(v);
    }
  }
  short8 a2[4];
#pragma unroll
  for (int ks = 0; ks < 4; ++ks)
    a2[ks] = as_short8(*(const uint4*)(&sX[wid][r][ks * 32 + quad * 8]));
#pragma unroll
  for (int nt = 0; nt < 4; ++nt) {
    f32x4 acc = {0.f, 0.f, 0.f, 0.f};
#pragma unroll
    for (int ks = 0; ks < 4; ++ks) {
      short8 b = as_short8(
          *(const uint4*)(Wt3 + (size_t)(nt * 16 + r) * 128 + ks * 32 + quad * 8));
      acc = __builtin_amdgcn_mfma_f32_16x16x32_bf16(a2[ks], b, acc, 0, 0, 0);
    }
#pragma unroll
    for (int reg = 0; reg < 4; ++reg) {
      int m = m16 + quad * 4 + reg;
      if (m < n) t3[(size_t)m * 64 + nt * 16 + r] = to_bf16(acc[reg]);
    }
  }
}

// ---------------- quad 64-feature bf16 CSR gather (NO private arrays) -----
// One wave gathers FOUR adjacent dst rows over combined csr range [rs,re),
// boundaries rm1<rm2<rm3. 128-edge index batches, 16 j-groups -> up to 16
// scattered uint4 loads in flight. Accumulators are 16 NAMED f32x2 vars
// (sets A,B,C,D x regs 0..3); all accumulator identity is compile-time
// (uniform if/else chains + value ternaries) -> no alloca, no scratch.

#define DECL_ACC(S) \
  f32x2 S##0 = {0, 0}, S##1 = {0, 0}, S##2 = {0, 0}, S##3 = {0, 0}

#define ADD8(S, v)   \
  {                  \
    S##0 += bf2((v).x); \
    S##1 += bf2((v).y); \
    S##2 += bf2((v).z); \
    S##3 += bf2((v).w); \
  }

#define ADD8M(S, v, m)     \
  {                        \
    uint4 _vm;             \
    _vm.x = (v).x & (m);   \
    _vm.y = (v).y & (m);   \
    _vm.z = (v).z & (m);   \
    _vm.w = (v).w & (m);   \
    ADD8(S, _vm);          \
  }

#define BFLY1(c)                   \
  {                                \
    c.x += __shfl_xor(c.x, 8);     \
    c.x += __shfl_xor(c.x, 16);    \
    c.x += __shfl_xor(c.x, 32);    \
    c.y += __shfl_xor(c.y, 8);     \
    c.y += __shfl_xor(c.y, 16);    \
    c.y += __shfl_xor(c.y, 32);    \
  }
#define BFLY4(S) \
  { BFLY1(S##0); BFLY1(S##1); BFLY1(S##2); BFLY1(S##3); }

// after butterfly: select set by per-lane eg (values only, compile-time k)
#define SELK(k)                                              \
  ((eg & 2) ? ((eg & 1) ? D##k : C##k) : ((eg & 1) ? B##k : A##k))

#define GATHER4(csr_, x_, rs_, rm1_, rm2_, rm3_, re_)                         \
  {                                                                           \
    for (int e0 = (rs_); e0 < (re_); e0 += 128) {                             \
      int i1 = e0 + lane, i2 = e0 + 64 + lane;                                \
      int sv0 = (i1 < (re_)) ? (csr_)[i1] : 0;                                \
      int sv1 = (i2 < (re_)) ? (csr_)[i2] : 0;                                \
      int cnt = (re_)-e0;                                                     \
      if (cnt > 128) cnt = 128;                                               \
      int c1 = (rm1_)-e0, c2 = (rm2_)-e0, c3 = (rm3_)-e0;                     \
      _Pragma("unroll") for (int j = 0; j < 16; ++j) {                        \
        int jb = j * 8;                                                       \
        if (jb < cnt) { /* wave-uniform */                                    \
          int s = __shfl((j < 8) ? sv0 : sv1, (jb & 63) + eg);                \
          uint4 v = *(const uint4*)((x_) + (size_t)s * 64 + fl * 8);          \
          if (jb + 8 > cnt) {                                                 \
            uint mv = ((jb + eg) < cnt) ? 0xffffffffu : 0u;                   \
            v.x &= mv; v.y &= mv; v.z &= mv; v.w &= mv;                       \
          }                                                                   \
          int slo = (jb >= c1) + (jb >= c2) + (jb >= c3);                     \
          int shi = (jb + 7 >= c1) + (jb + 7 >= c2) + (jb + 7 >= c3);         \
          if (slo == shi) { /* single-segment fast path, uniform */           \
            if (slo == 0) ADD8(A, v)                                          \
            else if (slo == 1) ADD8(B, v)                                     \
            else if (slo == 2) ADD8(C, v)                                     \
            else ADD8(D, v)                                                   \
          } else { /* straddle: only present segments, compile-time t */      \
            int p = jb + eg;                                                  \
            int sp = (p >= c1) + (p >= c2) + (p >= c3);                       \
            if (slo == 0) { uint m = (sp == 0) ? 0xffffffffu : 0u;            \
                            ADD8M(A, v, m) }                                  \
            if (slo <= 1 && shi >= 1) { uint m = (sp == 1) ? 0xffffffffu : 0u;\
                            ADD8M(B, v, m) }                                  \
            if (slo <= 2 && shi >= 2) { uint m = (sp == 2) ? 0xffffffffu : 0u;\
                            ADD8M(C, v, m) }                                  \
            if (shi == 3) { uint m = (sp == 3) ? 0xffffffffu : 0u;            \
                            ADD8M(D, v, m) }                                  \
          }                                                                   \
        }                                                                     \
      }                                                                       \
    }                                                                         \
    BFLY4(A); BFLY4(B); BFLY4(C); BFLY4(D);                                   \
  }

// ---------------- layer 1 aggregate + epilogue (bf16 out) ----------------
// h1s[n][j] = bf16(relu(seg(t1)*nd + b1[j]) * ns[n]); 4 nodes/wave.

__global__ __launch_bounds__(256) void agg1_kernel(
    const int* __restrict__ row_off, const int* __restrict__ csr,
    const ushort* __restrict__ t, const float* __restrict__ nd,
    const float* __restrict__ ns, const float* __restrict__ b,
    ushort* __restrict__ out, int n) {
  int wid = threadIdx.x >> 6, lane = threadIdx.x & 63;
  int eg = lane >> 3, fl = lane & 7;
  int n0 = blockIdx.x * 16 + wid * 4;  // n % 16 == 0
  int rs = row_off[n0], rm1 = row_off[n0 + 1], rm2 = row_off[n0 + 2],
      rm3 = row_off[n0 + 3], re = row_off[n0 + 4];
  DECL_ACC(A); DECL_ACC(B); DECL_ACC(C); DECL_ACC(D);
  GATHER4(csr, t, rs, rm1, rm2, rm3, re);
  if (eg < 4) {
    int node = n0 + eg;
    float ndv = nd[node], nsv = ns[node];
    const float4* bp = (const float4*)(b + fl * 8);
    float4 b0 = bp[0], b1v = bp[1];
    f32x2 s0 = SELK(0), s1 = SELK(1), s2 = SELK(2), s3 = SELK(3);
    float o0 = fmaxf(s0.x * ndv + b0.x, 0.f) * nsv;
    float o1 = fmaxf(s0.y * ndv + b0.y, 0.f) * nsv;
    float o2 = fmaxf(s1.x * ndv + b0.z, 0.f) * nsv;
    float o3 = fmaxf(s1.y * ndv + b0.w, 0.f) * nsv;
    float o4 = fmaxf(s2.x * ndv + b1v.x, 0.f) * nsv;
    float o5 = fmaxf(s2.y * ndv + b1v.y, 0.f) * nsv;
    float o6 = fmaxf(s3.x * ndv + b1v.z, 0.f) * nsv;
    float o7 = fmaxf(s3.y * ndv + b1v.w, 0.f) * nsv;
    uint4 v;
    v.x = pack_bf16(o0, o1);
    v.y = pack_bf16(o2, o3);
    v.z = pack_bf16(o4, o5);
    v.w = pack_bf16(o6, o7);
    *(uint4*)(out + (size_t)node * 64 + fl * 8) = v;
  }
}

// ---------------- layer 2 aggregate (gather-only, bf16 out) ----------------

__global__ __launch_bounds__(256) void agg2_kernel(
    const int* __restrict__ row_off, const int* __restrict__ csr,
    const ushort* __restrict__ h1s, const float* __restrict__ nd,
    ushort* __restrict__ m2, int n) {
  int wid = threadIdx.x >> 6, lane = threadIdx.x & 63;
  int eg = lane >> 3, fl = lane & 7;
  int n0 = blockIdx.x * 16 + wid * 4;
  int rs = row_off[n0], rm1 = row_off[n0 + 1], rm2 = row_off[n0 + 2],
      rm3 = row_off[n0 + 3], re = row_off[n0 + 4];
  DECL_ACC(A); DECL_ACC(B); DECL_ACC(C); DECL_ACC(D);
  GATHER4(csr, h1s, rs, rm1, rm2, rm3, re);
  if (eg < 4) {
    int node = n0 + eg;
    float ndv = nd[node];
    f32x2 s0 = SELK(0), s1 = SELK(1), s2 = SELK(2), s3 = SELK(3);
    uint4 v;
    v.x = pack_bf16(s0.x * ndv, s0.y * ndv);
    v.y = pack_bf16(s1.x * ndv, s1.y * ndv);
    v.z = pack_bf16(s2.x * ndv, s2.y * ndv);
    v.w = pack_bf16(s3.x * ndv, s3.y * ndv);
    *(uint4*)(m2 + (size_t)node * 64 + fl * 8) = v;
  }
}

// ---------------- layer 3 aggregate + block-reduced readout ----------------
// 512 threads = 8 waves x 4 nodes = 32 nodes/block; LDS tree-reduce ->
// ~1 atomic row per block (gids sorted: ~98% of blocks gid-uniform).

__global__ __launch_bounds__(512) void agg3_kernel(
    const int* __restrict__ row_off, const int* __restrict__ csr,
    const ushort* __restrict__ t, const float* __restrict__ nd,
    const float* __restrict__ b, const int* __restrict__ gid,
    float* __restrict__ hg, int n) {
  __shared__ float sO[32][64];
  __shared__ int sG[32];
  __shared__ int uni;
  int wid = threadIdx.x >> 6, lane = threadIdx.x & 63;
  int eg = lane >> 3, fl = lane & 7;
  int n0 = blockIdx.x * 32 + wid * 4;  // NN % 32 == 0
  int rs = row_off[n0], rm1 = row_off[n0 + 1], rm2 = row_off[n0 + 2],
      rm3 = row_off[n0 + 3], re = row_off[n0 + 4];
  DECL_ACC(A); DECL_ACC(B); DECL_ACC(C); DECL_ACC(D);
  GATHER4(csr, t, rs, rm1, rm2, rm3, re);
  if (eg < 4) {
    int node = n0 + eg;
    int row = wid * 4 + eg;
    float ndv = nd[node];
    const float4* bp = (const float4*)(b + fl * 8);
    float4 b0 = bp[0], b1v = bp[1];
    f32x2 s0 = SELK(0), s1 = SELK(1), s2 = SELK(2), s3 = SELK(3);
    sO[row][fl * 8 + 0] = fmaxf(s0.x * ndv + b0.x, 0.f);
    sO[row][fl * 8 + 1] = fmaxf(s0.y * ndv + b0.y, 0.f);
    sO[row][fl * 8 + 2] = fmaxf(s1.x * ndv + b0.z, 0.f);
    sO[row][fl * 8 + 3] = fmaxf(s1.y * ndv + b0.w, 0.f);
    sO[row][fl * 8 + 4] = fmaxf(s2.x * ndv + b1v.x, 0.f);
    sO[row][fl * 8 + 5] = fmaxf(s2.y * ndv + b1v.y, 0.f);
    sO[row][fl * 8 + 6] = fmaxf(s3.x * ndv + b1v.z, 0.f);
    sO[row][fl * 8 + 7] = fmaxf(s3.y * ndv + b1v.w, 0.f);
    if (fl == 0) sG[row] = gid[node];
  }
  __syncthreads();
  if (threadIdx.x == 0) {
    int g0 = sG[0], u = 1;
#pragma unroll
    for (int i = 1; i < 32; ++i) u &= (sG[i] == g0);
    uni = u;
  }
  __syncthreads();
  if (uni) {
    int r = threadIdx.x >> 6;  // 0..7
#pragma unroll
    for (int s = 16; s >= 1; s >>= 1) {
      for (int rr = r; rr < s; rr += 8) sO[rr][lane] += sO[rr + s][lane];
      __syncthreads();
    }
    if (threadIdx.x < 64) atomicAdd(&hg[sG[0] * 64 + lane], sO[0][lane]);
  } else {
#pragma unroll
    for (int i = 0; i < 4; ++i) {
      int row = wid * 4 + i;
      atomicAdd(&hg[sG[row] * 64 + lane], sO[row][lane]);
    }
  }
}

// ---------------- readout dense ----------------

__global__ __launch_bounds__(640) void readout_kernel(
    const float* __restrict__ hg, const float* __restrict__ Wd,
    const float* __restrict__ bd, float* __restrict__ out) {
  int t = threadIdx.x;  // 640 = 64 graphs * 10 classes
  int g = t / 10, c = t % 10;
  float o = bd[c];
#pragma unroll 8
  for (int k = 0; k < 64; ++k) o += tanhf(hg[g * 64 + k]) * Wd[k * 10 + c];
  out[t] = o;
}

// ---------------- launch ----------------

extern "C" void kernel_launch(void* const* d_in, const int* in_sizes, int n_in,
                              void* d_out, int out_size, void* d_ws, size_t ws_size,
                              hipStream_t stream) {
  const float* in_feat = (const float*)d_in[0];
  const int* src = (const int*)d_in[1];
  const int* dst = (const int*)d_in[2];
  const int* gid = (const int*)d_in[3];
  const float* W1 = (const float*)d_in[4];
  const float* b1 = (const float*)d_in[5];
  const float* W2 = (const float*)d_in[6];
  const float* b2 = (const float*)d_in[7];
  const float* W3 = (const float*)d_in[8];
  const float* b3 = (const float*)d_in[9];
  const float* Wd = (const float*)d_in[10];
  const float* bd = (const float*)d_in[11];
  float* out = (float*)d_out;

  char* ws = (char*)d_ws;
  size_t o = 0;
  auto alloc = [&](size_t bytes) -> char* {
    char* p = ws + o;
    o = (o + bytes + 1023) & ~(size_t)1023;
    return p;
  };
  float* hg = (float*)alloc(NG * 64 * 4);
  size_t zero_bytes = o;  // only hg needs zero-init
  int* deg_in = (int*)alloc(NN * 4);
  float* norm_src = (float*)alloc(NN * 4);
  float* norm_dst = (float*)alloc(NN * 4);
  int* row_off = (int*)alloc((NN + 1) * 4);
  int* bsums = (int*)alloc(512);
  ushort* Wt1 = (ushort*)alloc(64 * 128 * 2);
  ushort* Wt2 = (ushort*)alloc(128 * 64 * 2);
  ushort* Wt3 = (ushort*)alloc(64 * 128 * 2);
  int* csr = (int*)alloc((size_t)NE * 4);
  ushort* tbuf = (ushort*)alloc((size_t)NN * 64 * 2);  // bf16 t1, then t3
  ushort* h1s = (ushort*)alloc((size_t)NN * 64 * 2);   // bf16
  ushort* m2 = (ushort*)alloc((size_t)NN * 64 * 2);    // bf16
  (void)ws_size;

  // overlays on [tbuf..) (38.4MB contiguous): all CSR-build scratch is dead
  // before gemm1 (tbuf), agg1 (h1s), agg2 (m2) first write.
  char* ov = (char*)tbuf;
  uint* pdst = (uint*)ov;                                 // 2.45MB
  uint* psrc = (uint*)(ov + 2457600);                     // 2.45MB
  unsigned char* Pb = (unsigned char*)(ov + 4915200);     // 4.9MB
  unsigned char* lrank = (unsigned char*)(ov + 9830400);  // 3.2MB

  hipMemsetAsync(d_ws, 0, zero_bytes, stream);

  const int egrid = (NE + 255) / 256;      // 12500
  const int ngrid = (NN + 255) / 256;      // 391
  const int sgrid = (NN + 1023) / 1024;    // 98
  const int qgrid = NN / 16;               // 6250 (quad-gather, 4 waves/blk)
  const int rgrid = (WORDS4 + 255) / 256;  // 49
  const int ggrid = (NN + 63) / 64;        // 1563

  transw_kernel<<<96, 256, 0, stream>>>(W1, W2, W3, Wt1, Wt2, Wt3);
  hist_kernel<<<dim3(NCHUNK, 2), 1024, 0, stream>>>(src, dst, pdst, psrc, lrank);
  reduce2_kernel<<<dim3(rgrid, 2), 256, 0, stream>>>(pdst, psrc, Pb, deg_in,
                                                     norm_dst, norm_src);
  scan1_kernel<<<sgrid, 256, 0, stream>>>(deg_in, row_off, bsums, NN);
  scan2_kernel<<<1, 128, 0, stream>>>(bsums, sgrid, row_off, NN);
  scan3_kernel<<<ngrid, 256, 0, stream>>>(row_off, bsums, NN);
  fill_kernel<<<egrid, 256, 0, stream>>>(src, dst, row_off, Pb, lrank, csr, NE);

  // layer 1: t1 = bf16((in_feat @ W1) * ns)   [MFMA]
  gemm1_kernel<<<ggrid, 256, 0, stream>>>(in_feat, Wt1, norm_src, tbuf, NN);
  // h1s = bf16(relu(seg(t1)*nd + b1) * ns)
  agg1_kernel<<<qgrid, 256, 0, stream>>>(row_off, csr, tbuf, norm_dst,
                                         norm_src, b1, h1s, NN);
  // m2 = bf16(seg(h1s)*nd)
  agg2_kernel<<<qgrid, 256, 0, stream>>>(row_off, csr, h1s, norm_dst, m2, NN);
  // t3 = bf16((relu(m2@W2+b2)*ns) @ W3)   [fused MFMA x2]
  gemm23_kernel<<<ggrid, 256, 0, stream>>>(m2, Wt2, b2, norm_src, Wt3, tbuf, NN);
  // hg[g] += relu(seg(t3)*nd + b3)
  agg3_kernel<<<NN / 32, 512, 0, stream>>>(row_off, csr, tbuf, norm_dst, b3,
                                           gid, hg, NN);
  readout_kernel<<<1, 640, 0, stream>>>(hg, Wd, bd, out);
}

// Round 10
// 457.714 us; speedup vs baseline: 2.5416x; 1.1150x over previous
//
#include <hip/hip_runtime.h>
#include <hip/hip_bf16.h>

// GCN: 3x GraphConv(norm='both') + graph readout + dense head.
// Strategy:
//  - ATOMIC-FREE CSR build (R2: device atomics cap ~26G/s):
//      hist (4-bit packed full-range LDS bins, CBITS=16) -> reduce2 (nibble
//      sums + fused norms) -> scan -> fill.
//  - Algebra: transform-first for 128->64 layers so ALL gathers are 64-feat.
//  - bf16 features; 8 lanes/edge uint4 loads (R3); ALL dense multiplies are
//    MFMA 16x16x32 bf16 (R4); gemm2+gemm3 fused via LDS tile (R6).
//  - R5: PAIR-GATHER: one wave = 2 adjacent dst nodes over their combined
//    contiguous csr range (avg 64 edges = one wave index load); j-groups of
//    8 edges routed to acc0/acc1 by wave-uniform boundary.
//  - R7-R9 lesson (MEASURED): quad-gather (4 nodes/wave) LOSES. With
//    runtime-indexed private acc arrays it scratch-demotes (465MB writes,
//    2.5x regression); even with named accumulators it runs 112 vs 74 us
//    (occupancy 65->40%, +40% routing VALU). Pair-gather is the optimum
//    operating point for this graph (74us/agg, VALU 41%, ~5.7 TB/s eff).
//  - agg3: block LDS-reduce 16 nodes -> ~1 atomic row/block.

constexpr int NN = 100000;   // nodes
constexpr int NE = 3200000;  // edges
constexpr int NG = 64;       // graphs

constexpr int CBITS = 16;
constexpr int CHUNK = 1 << CBITS;                 // 65536 edges/chunk
constexpr int NCHUNK = (NE + CHUNK - 1) / CHUNK;  // 49
constexpr int WORDS4 = NN / 8;                    // 12500 packed u4x8 words

typedef __attribute__((ext_vector_type(8))) short short8;
typedef __attribute__((ext_vector_type(4))) float f32x4;
typedef __attribute__((ext_vector_type(2))) float f32x2;

// ---------------- chunked LDS histogram (4-bit bins, full node range) -----
// Per-chunk-per-node counts <=15 (Poisson(0.65); overflow P ~ 1e-9). y picks
// dst (also records local rank from the LDS-atomic return) or src.

__global__ __launch_bounds__(1024) void hist_kernel(
    const int* __restrict__ src, const int* __restrict__ dst,
    uint* __restrict__ pdst, uint* __restrict__ psrc,
    unsigned char* __restrict__ lrank) {
  __shared__ uint bins[WORDS4];  // 50KB
  for (int i = threadIdx.x; i < WORDS4; i += 1024) bins[i] = 0;
  __syncthreads();
  const int c = blockIdx.x;
  const int start = c << CBITS;
  const int end = min(start + CHUNK, NE);
  if (blockIdx.y == 0) {
    for (int i = start + threadIdx.x; i < end; i += 1024) {
      int n = dst[i];
      uint old = atomicAdd(&bins[n >> 3], 1u << ((n & 7) * 4));
      lrank[i] = (unsigned char)((old >> ((n & 7) * 4)) & 0xf);
    }
  } else {
    for (int i = start + threadIdx.x; i < end; i += 1024) {
      int n = src[i];
      atomicAdd(&bins[n >> 3], 1u << ((n & 7) * 4));
    }
  }
  __syncthreads();
  uint* pp = ((blockIdx.y == 0) ? pdst : psrc) + (size_t)c * WORDS4;
  for (int i = threadIdx.x; i < WORDS4; i += 1024) pp[i] = bins[i];
}

// ------- reduce2: nibble sums -> deg_in + chunk-exclusive prefix + norms ---
// y==0: pdst -> (P bytes, deg_in, nd);  y==1: psrc -> ns.

__global__ __launch_bounds__(256) void reduce2_kernel(
    const uint* __restrict__ pdst, const uint* __restrict__ psrc,
    unsigned char* __restrict__ Pb, int* __restrict__ deg_in,
    float* __restrict__ nd, float* __restrict__ ns) {
  int w = blockIdx.x * 256 + threadIdx.x;
  if (w >= WORDS4) return;
  uint run[8] = {0, 0, 0, 0, 0, 0, 0, 0};
  if (blockIdx.y == 0) {
#pragma unroll 7
    for (int c = 0; c < NCHUNK; ++c) {
      uint lo = run[0] | (run[1] << 8) | (run[2] << 16) | (run[3] << 24);
      uint hi = run[4] | (run[5] << 8) | (run[6] << 16) | (run[7] << 24);
      ((uint2*)(Pb + (size_t)c * NN))[w] = make_uint2(lo, hi);
      uint v = pdst[(size_t)c * WORDS4 + w];
#pragma unroll
      for (int k = 0; k < 8; ++k) run[k] += (v >> (4 * k)) & 0xfu;
    }
    ((int4*)deg_in)[2 * w] = make_int4(run[0], run[1], run[2], run[3]);
    ((int4*)deg_in)[2 * w + 1] = make_int4(run[4], run[5], run[6], run[7]);
    float4 f0, f1;
    f0.x = rsqrtf(fmaxf((float)run[0], 1.f));
    f0.y = rsqrtf(fmaxf((float)run[1], 1.f));
    f0.z = rsqrtf(fmaxf((float)run[2], 1.f));
    f0.w = rsqrtf(fmaxf((float)run[3], 1.f));
    f1.x = rsqrtf(fmaxf((float)run[4], 1.f));
    f1.y = rsqrtf(fmaxf((float)run[5], 1.f));
    f1.z = rsqrtf(fmaxf((float)run[6], 1.f));
    f1.w = rsqrtf(fmaxf((float)run[7], 1.f));
    ((float4*)nd)[2 * w] = f0;
    ((float4*)nd)[2 * w + 1] = f1;
  } else {
#pragma unroll 7
    for (int c = 0; c < NCHUNK; ++c) {
      uint v = psrc[(size_t)c * WORDS4 + w];
#pragma unroll
      for (int k = 0; k < 8; ++k) run[k] += (v >> (4 * k)) & 0xfu;
    }
    float4 f0, f1;
    f0.x = rsqrtf(fmaxf((float)run[0], 1.f));
    f0.y = rsqrtf(fmaxf((float)run[1], 1.f));
    f0.z = rsqrtf(fmaxf((float)run[2], 1.f));
    f0.w = rsqrtf(fmaxf((float)run[3], 1.f));
    f1.x = rsqrtf(fmaxf((float)run[4], 1.f));
    f1.y = rsqrtf(fmaxf((float)run[5], 1.f));
    f1.z = rsqrtf(fmaxf((float)run[6], 1.f));
    f1.w = rsqrtf(fmaxf((float)run[7], 1.f));
    ((float4*)ns)[2 * w] = f0;
    ((float4*)ns)[2 * w + 1] = f1;
  }
}

// ---------------- exclusive scan (1024 elems / block) ----------------

__global__ __launch_bounds__(256) void scan1_kernel(
    const int* __restrict__ deg, int* __restrict__ row_off,
    int* __restrict__ bsums, int n) {
  __shared__ int s[256];
  int t = threadIdx.x;
  int base = blockIdx.x * 1024 + t * 4;
  int v0 = 0, v1 = 0, v2 = 0, v3 = 0;
  if (base + 0 < n) v0 = deg[base + 0];
  if (base + 1 < n) v1 = deg[base + 1];
  if (base + 2 < n) v2 = deg[base + 2];
  if (base + 3 < n) v3 = deg[base + 3];
  int sum = v0 + v1 + v2 + v3;
  s[t] = sum;
  __syncthreads();
  for (int off = 1; off < 256; off <<= 1) {
    int x = (t >= off) ? s[t - off] : 0;
    __syncthreads();
    s[t] += x;
    __syncthreads();
  }
  int excl = s[t] - sum;
  if (t == 255) bsums[blockIdx.x] = s[255];
  if (base + 0 < n) row_off[base + 0] = excl;
  if (base + 1 < n) row_off[base + 1] = excl + v0;
  if (base + 2 < n) row_off[base + 2] = excl + v0 + v1;
  if (base + 3 < n) row_off[base + 3] = excl + v0 + v1 + v2;
}

__global__ __launch_bounds__(128) void scan2_kernel(
    int* __restrict__ bsums, int nb, int* __restrict__ row_off, int n) {
  __shared__ int s[128];
  int t = threadIdx.x;
  int v = (t < nb) ? bsums[t] : 0;
  s[t] = v;
  __syncthreads();
  for (int off = 1; off < 128; off <<= 1) {
    int x = (t >= off) ? s[t - off] : 0;
    __syncthreads();
    s[t] += x;
    __syncthreads();
  }
  if (t < nb) bsums[t] = s[t] - v;
  if (t == 127) row_off[n] = s[127];
}

__global__ __launch_bounds__(256) void scan3_kernel(
    int* __restrict__ row_off, const int* __restrict__ bsums, int n) {
  int i = blockIdx.x * 256 + threadIdx.x;
  if (i < n) row_off[i] += bsums[i >> 10];
}

// ---------------- CSR fill (atomic-free) ----------------

__global__ __launch_bounds__(256) void fill_kernel(
    const int* __restrict__ src, const int* __restrict__ dst,
    const int* __restrict__ row_off, const unsigned char* __restrict__ Pb,
    const unsigned char* __restrict__ lrank, int* __restrict__ csr, int e) {
  int i = blockIdx.x * 256 + threadIdx.x;
  if (i < e) {
    int d = dst[i];
    int c = i >> CBITS;
    int pos = row_off[d] + (int)Pb[(size_t)c * NN + d] + (int)lrank[i];
    csr[pos] = src[i];
  }
}

// ---------------- bf16 helpers ----------------

__device__ __forceinline__ uint pack_bf16(float a, float b) {
  uint ua = __float_as_uint(a), ub = __float_as_uint(b);
  ua = (ua + 0x7fffu + ((ua >> 16) & 1u)) >> 16;          // RNE
  ub = (ub + 0x7fffu + ((ub >> 16) & 1u)) & 0xffff0000u;  // RNE
  return ua | ub;  // a -> low ushort (even idx), b -> high (odd idx)
}

__device__ __forceinline__ ushort to_bf16(float a) {
  uint ua = __float_as_uint(a);
  return (ushort)((ua + 0x7fffu + ((ua >> 16) & 1u)) >> 16);
}

union U16 {
  uint4 u;
  short8 s;
};
__device__ __forceinline__ short8 as_short8(uint4 u) {
  U16 t;
  t.u = u;
  return t.s;
}

__device__ __forceinline__ f32x2 bf2(uint u) {
  f32x2 r;
  r.x = __uint_as_float(u << 16);
  r.y = __uint_as_float(u & 0xffff0000u);
  return r;
}

__device__ __forceinline__ void add8(f32x2* a, uint4 v) {
  a[0] += bf2(v.x);
  a[1] += bf2(v.y);
  a[2] += bf2(v.z);
  a[3] += bf2(v.w);
}

// ---------------- weight transpose + bf16 convert ----------------

__global__ __launch_bounds__(256) void transw_kernel(
    const float* __restrict__ W1, const float* __restrict__ W2,
    const float* __restrict__ W3, ushort* __restrict__ Wt1,
    ushort* __restrict__ Wt2, ushort* __restrict__ Wt3) {
  int i = blockIdx.x * 256 + threadIdx.x;  // 0..24575
  if (i < 8192) {
    int n = i >> 7, k = i & 127;
    Wt1[i] = to_bf16(W1[k * 64 + n]);
  } else if (i < 16384) {
    int j = i - 8192;
    int n = j >> 6, k = j & 63;
    Wt2[j] = to_bf16(W2[k * 128 + n]);
  } else if (i < 24576) {
    int j = i - 16384;
    int n = j >> 7, k = j & 127;
    Wt3[j] = to_bf16(W3[k * 64 + n]);
  }
}

// ---------------- skinny MFMA GEMM (layer 1): t1 = bf16((A@W1)*ns) --------
// A: [n][128] fp32 (inline bf16 convert), Wt: [64][128] bf16, C: [n][64].
// mfma_f32_16x16x32_bf16: A-frag A[m=lane&15][k=quad*8+j], C/D col=lane&15,
// row=quad*4+reg  [learn_hip m89 verified].

__global__ __launch_bounds__(256) void gemm1_kernel(
    const float* __restrict__ A, const ushort* __restrict__ Wt,
    const float* __restrict__ scale, ushort* __restrict__ C, int n) {
  int wid = threadIdx.x >> 6, lane = threadIdx.x & 63;
  int r = lane & 15, quad = lane >> 4;
  int m16 = blockIdx.x * 64 + wid * 16;
  if (m16 >= n) return;
  int mc = min(m16 + r, n - 1);
  short8 a[4];
#pragma unroll
  for (int ks = 0; ks < 4; ++ks) {
    const float4* p = (const float4*)(A + (size_t)mc * 128 + ks * 32 + quad * 8);
    float4 x = p[0], y = p[1];
    uint4 u;
    u.x = pack_bf16(x.x, x.y);
    u.y = pack_bf16(x.z, x.w);
    u.z = pack_bf16(y.x, y.y);
    u.w = pack_bf16(y.z, y.w);
    a[ks] = as_short8(u);
  }
#pragma unroll
  for (int nt = 0; nt < 4; ++nt) {
    f32x4 acc = {0.f, 0.f, 0.f, 0.f};
#pragma unroll
    for (int ks = 0; ks < 4; ++ks) {
      short8 b = as_short8(
          *(const uint4*)(Wt + (size_t)(nt * 16 + r) * 128 + ks * 32 + quad * 8));
      acc = __builtin_amdgcn_mfma_f32_16x16x32_bf16(a[ks], b, acc, 0, 0, 0);
    }
#pragma unroll
    for (int reg = 0; reg < 4; ++reg) {
      int m = m16 + quad * 4 + reg;
      if (m < n) C[(size_t)m * 64 + nt * 16 + r] = to_bf16(acc[reg] * scale[m]);
    }
  }
}

// ------- fused layers 2+3 dense: t3 = (relu(m2@W2+b2)*ns) @ W3 ------------
// First MFMA (K=64,N=128) -> epilogue -> bf16 tile in LDS (padded 136) ->
// A-frags for second MFMA (K=128,N=64). Same-wave LDS write->read only.

__global__ __launch_bounds__(256) void gemm23_kernel(
    const ushort* __restrict__ m2, const ushort* __restrict__ Wt2,
    const float* __restrict__ b2, const float* __restrict__ ns,
    const ushort* __restrict__ Wt3, ushort* __restrict__ t3, int n) {
  __shared__ ushort sX[4][16][136];  // 17.4KB, pad keeps 16B align
  int wid = threadIdx.x >> 6, lane = threadIdx.x & 63;
  int r = lane & 15, quad = lane >> 4;
  int m16 = blockIdx.x * 64 + wid * 16;
  if (m16 >= n) return;
  int mc = min(m16 + r, n - 1);
  short8 a1[2];
#pragma unroll
  for (int ks = 0; ks < 2; ++ks)
    a1[ks] = as_short8(*(const uint4*)(m2 + (size_t)mc * 64 + ks * 32 + quad * 8));
  float nsv[4];
#pragma unroll
  for (int reg = 0; reg < 4; ++reg)
    nsv[reg] = ns[min(m16 + quad * 4 + reg, n - 1)];
#pragma unroll
  for (int nt = 0; nt < 8; ++nt) {
    f32x4 acc = {0.f, 0.f, 0.f, 0.f};
#pragma unroll
    for (int ks = 0; ks < 2; ++ks) {
      short8 b = as_short8(
          *(const uint4*)(Wt2 + (size_t)(nt * 16 + r) * 64 + ks * 32 + quad * 8));
      acc = __builtin_amdgcn_mfma_f32_16x16x32_bf16(a1[ks], b, acc, 0, 0, 0);
    }
    float bv = b2[nt * 16 + r];
#pragma unroll
    for (int reg = 0; reg < 4; ++reg) {
      float v = fmaxf(acc[reg] + bv, 0.f) * nsv[reg];
      sX[wid][quad * 4 + reg][nt * 16 + r] = to_bf16(v);
    }
  }
  short8 a2[4];
#pragma unroll
  for (int ks = 0; ks < 4; ++ks)
    a2[ks] = as_short8(*(const uint4*)(&sX[wid][r][ks * 32 + quad * 8]));
#pragma unroll
  for (int nt = 0; nt < 4; ++nt) {
    f32x4 acc = {0.f, 0.f, 0.f, 0.f};
#pragma unroll
    for (int ks = 0; ks < 4; ++ks) {
      short8 b = as_short8(
          *(const uint4*)(Wt3 + (size_t)(nt * 16 + r) * 128 + ks * 32 + quad * 8));
      acc = __builtin_amdgcn_mfma_f32_16x16x32_bf16(a2[ks], b, acc, 0, 0, 0);
    }
#pragma unroll
    for (int reg = 0; reg < 4; ++reg) {
      int m = m16 + quad * 4 + reg;
      if (m < n) t3[(size_t)m * 64 + nt * 16 + r] = to_bf16(acc[reg]);
    }
  }
}

// ---------------- paired 64-feature bf16 CSR gather ----------------
// One wave gathers TWO adjacent dst rows over the combined contiguous csr
// range [rs, re), boundary rm. 8 lanes/edge, uint4 = 8 bf16 features/lane.
// j-groups of 8 edges route to acc0/acc1 by the wave-uniform boundary
// c0 = rm - e0; only the straddling group pays a mask split. Butterfly at
// the end leaves every lane with both nodes' 8-feature totals.

__device__ __forceinline__ void gather2_bf16(const int* __restrict__ csr,
                                             const ushort* __restrict__ x,
                                             int rs, int rm, int re, int lane,
                                             f32x2* a0, f32x2* a1) {
  const int eg = lane >> 3;
  const int fl = lane & 7;
  for (int e0 = rs; e0 < re; e0 += 64) {
    int idx = e0 + lane;
    int sv = (idx < re) ? csr[idx] : 0;
    int cnt = re - e0;
    if (cnt > 64) cnt = 64;
    int c0 = rm - e0;  // slots < c0 belong to node0
#pragma unroll
    for (int j = 0; j < 8; ++j) {
      int jb = j * 8;
      if (jb < cnt) {  // wave-uniform
        int s = __shfl(sv, jb + eg);
        uint4 v = *(const uint4*)(x + (size_t)s * 64 + fl * 8);
        if (jb + 8 > cnt) {  // partial tail: mask invalid edge-groups
          uint mv = ((jb + eg) < cnt) ? 0xffffffffu : 0u;
          v.x &= mv; v.y &= mv; v.z &= mv; v.w &= mv;
        }
        if (jb + 8 <= c0) {
          add8(a0, v);
        } else if (jb >= c0) {
          add8(a1, v);
        } else {  // straddles the node boundary
          uint m0 = ((jb + eg) < c0) ? 0xffffffffu : 0u;
          uint4 v0;
          v0.x = v.x & m0; v0.y = v.y & m0; v0.z = v.z & m0; v0.w = v.w & m0;
          add8(a0, v0);
          v.x ^= v0.x; v.y ^= v0.y; v.z ^= v0.z; v.w ^= v0.w;
          add8(a1, v);
        }
      }
    }
  }
#pragma unroll
  for (int k = 0; k < 4; ++k) {
    a0[k].x += __shfl_xor(a0[k].x, 8);
    a0[k].x += __shfl_xor(a0[k].x, 16);
    a0[k].x += __shfl_xor(a0[k].x, 32);
    a0[k].y += __shfl_xor(a0[k].y, 8);
    a0[k].y += __shfl_xor(a0[k].y, 16);
    a0[k].y += __shfl_xor(a0[k].y, 32);
    a1[k].x += __shfl_xor(a1[k].x, 8);
    a1[k].x += __shfl_xor(a1[k].x, 16);
    a1[k].x += __shfl_xor(a1[k].x, 32);
    a1[k].y += __shfl_xor(a1[k].y, 8);
    a1[k].y += __shfl_xor(a1[k].y, 16);
    a1[k].y += __shfl_xor(a1[k].y, 32);
  }
}

// select feature k (0..7) of the proper node's accumulator
#define ACC_SEL(k) ((eg == 0) ? a0[(k) >> 1][(k)&1] : a1[(k) >> 1][(k)&1])

// ---------------- layer 1 aggregate + epilogue (bf16 out) ----------------
// h1s[n][j] = bf16(relu(seg(t1)*nd + b1[j]) * ns[n]); 2 nodes/wave.

__global__ __launch_bounds__(256) void agg1_kernel(
    const int* __restrict__ row_off, const int* __restrict__ csr,
    const ushort* __restrict__ t, const float* __restrict__ nd,
    const float* __restrict__ ns, const float* __restrict__ b,
    ushort* __restrict__ out, int n) {
  int wid = threadIdx.x >> 6, lane = threadIdx.x & 63;
  int n0 = blockIdx.x * 8 + wid * 2;  // n % 8 == 0
  int rs = row_off[n0], rm = row_off[n0 + 1], re = row_off[n0 + 2];
  f32x2 a0[4] = {{0, 0}, {0, 0}, {0, 0}, {0, 0}};
  f32x2 a1[4] = {{0, 0}, {0, 0}, {0, 0}, {0, 0}};
  gather2_bf16(csr, t, rs, rm, re, lane, a0, a1);
  int eg = lane >> 3, fl = lane & 7;
  if (eg < 2) {  // eg==0 -> node0, eg==1 -> node1
    int node = n0 + eg;
    float ndv = nd[node], nsv = ns[node];
    const float4* bp = (const float4*)(b + fl * 8);
    float4 b0 = bp[0], b1v = bp[1];
    float o0 = fmaxf(ACC_SEL(0) * ndv + b0.x, 0.f) * nsv;
    float o1 = fmaxf(ACC_SEL(1) * ndv + b0.y, 0.f) * nsv;
    float o2 = fmaxf(ACC_SEL(2) * ndv + b0.z, 0.f) * nsv;
    float o3 = fmaxf(ACC_SEL(3) * ndv + b0.w, 0.f) * nsv;
    float o4 = fmaxf(ACC_SEL(4) * ndv + b1v.x, 0.f) * nsv;
    float o5 = fmaxf(ACC_SEL(5) * ndv + b1v.y, 0.f) * nsv;
    float o6 = fmaxf(ACC_SEL(6) * ndv + b1v.z, 0.f) * nsv;
    float o7 = fmaxf(ACC_SEL(7) * ndv + b1v.w, 0.f) * nsv;
    uint4 v;
    v.x = pack_bf16(o0, o1);
    v.y = pack_bf16(o2, o3);
    v.z = pack_bf16(o4, o5);
    v.w = pack_bf16(o6, o7);
    *(uint4*)(out + (size_t)node * 64 + fl * 8) = v;
  }
}

// ---------------- layer 2 aggregate (gather-only, bf16 out) ----------------
// m2[n][j] = bf16(seg(h1s)*nd); 2 nodes/wave.

__global__ __launch_bounds__(256) void agg2_kernel(
    const int* __restrict__ row_off, const int* __restrict__ csr,
    const ushort* __restrict__ h1s, const float* __restrict__ nd,
    ushort* __restrict__ m2, int n) {
  int wid = threadIdx.x >> 6, lane = threadIdx.x & 63;
  int n0 = blockIdx.x * 8 + wid * 2;
  int rs = row_off[n0], rm = row_off[n0 + 1], re = row_off[n0 + 2];
  f32x2 a0[4] = {{0, 0}, {0, 0}, {0, 0}, {0, 0}};
  f32x2 a1[4] = {{0, 0}, {0, 0}, {0, 0}, {0, 0}};
  gather2_bf16(csr, h1s, rs, rm, re, lane, a0, a1);
  int eg = lane >> 3, fl = lane & 7;
  if (eg < 2) {
    int node = n0 + eg;
    float ndv = nd[node];
    uint4 v;
    v.x = pack_bf16(ACC_SEL(0) * ndv, ACC_SEL(1) * ndv);
    v.y = pack_bf16(ACC_SEL(2) * ndv, ACC_SEL(3) * ndv);
    v.z = pack_bf16(ACC_SEL(4) * ndv, ACC_SEL(5) * ndv);
    v.w = pack_bf16(ACC_SEL(6) * ndv, ACC_SEL(7) * ndv);
    *(uint4*)(m2 + (size_t)node * 64 + fl * 8) = v;
  }
}

// ---------------- layer 3 aggregate + block-reduced readout ----------------
// 512 threads = 8 waves x 2 nodes = 16 nodes/block; LDS tree-reduce ->
// ~1 atomic row per block (gids sorted: nearly all blocks gid-uniform).

__global__ __launch_bounds__(512) void agg3_kernel(
    const int* __restrict__ row_off, const int* __restrict__ csr,
    const ushort* __restrict__ t, const float* __restrict__ nd,
    const float* __restrict__ b, const int* __restrict__ gid,
    float* __restrict__ hg, int n) {
  __shared__ float sO[16][64];
  __shared__ int sG[16];
  __shared__ int uni;
  int wid = threadIdx.x >> 6, lane = threadIdx.x & 63;
  int n0 = blockIdx.x * 16 + wid * 2;  // NN % 16 == 0
  int rs = row_off[n0], rm = row_off[n0 + 1], re = row_off[n0 + 2];
  f32x2 a0[4] = {{0, 0}, {0, 0}, {0, 0}, {0, 0}};
  f32x2 a1[4] = {{0, 0}, {0, 0}, {0, 0}, {0, 0}};
  gather2_bf16(csr, t, rs, rm, re, lane, a0, a1);
  int eg = lane >> 3, fl = lane & 7;
  if (eg < 2) {
    int node = n0 + eg;
    int row = wid * 2 + eg;
    float ndv = nd[node];
    const float4* bp = (const float4*)(b + fl * 8);
    float4 b0 = bp[0], b1v = bp[1];
    sO[row][fl * 8 + 0] = fmaxf(ACC_SEL(0) * ndv + b0.x, 0.f);
    sO[row][fl * 8 + 1] = fmaxf(ACC_SEL(1) * ndv + b0.y, 0.f);
    sO[row][fl * 8 + 2] = fmaxf(ACC_SEL(2) * ndv + b0.z, 0.f);
    sO[row][fl * 8 + 3] = fmaxf(ACC_SEL(3) * ndv + b0.w, 0.f);
    sO[row][fl * 8 + 4] = fmaxf(ACC_SEL(4) * ndv + b1v.x, 0.f);
    sO[row][fl * 8 + 5] = fmaxf(ACC_SEL(5) * ndv + b1v.y, 0.f);
    sO[row][fl * 8 + 6] = fmaxf(ACC_SEL(6) * ndv + b1v.z, 0.f);
    sO[row][fl * 8 + 7] = fmaxf(ACC_SEL(7) * ndv + b1v.w, 0.f);
  }
  if (lane == 0) sG[wid * 2] = gid[n0];
  if (lane == 8) sG[wid * 2 + 1] = gid[n0 + 1];
  __syncthreads();
  if (threadIdx.x == 0) {
    int g0 = sG[0], u = 1;
#pragma unroll
    for (int i = 1; i < 16; ++i) u &= (sG[i] == g0);
    uni = u;
  }
  __syncthreads();
  if (uni) {
    int r = threadIdx.x >> 6;  // 0..7
#pragma unroll
    for (int s = 8; s >= 1; s >>= 1) {
      if (r < s) sO[r][lane] += sO[r + s][lane];
      __syncthreads();
    }
    if (threadIdx.x < 64) atomicAdd(&hg[sG[0] * 64 + lane], sO[0][lane]);
  } else {
    atomicAdd(&hg[sG[wid * 2] * 64 + lane], sO[wid * 2][lane]);
    atomicAdd(&hg[sG[wid * 2 + 1] * 64 + lane], sO[wid * 2 + 1][lane]);
  }
}

// ---------------- readout dense ----------------

__global__ __launch_bounds__(640) void readout_kernel(
    const float* __restrict__ hg, const float* __restrict__ Wd,
    const float* __restrict__ bd, float* __restrict__ out) {
  int t = threadIdx.x;  // 640 = 64 graphs * 10 classes
  int g = t / 10, c = t % 10;
  float o = bd[c];
#pragma unroll 8
  for (int k = 0; k < 64; ++k) o += tanhf(hg[g * 64 + k]) * Wd[k * 10 + c];
  out[t] = o;
}

// ---------------- launch ----------------

extern "C" void kernel_launch(void* const* d_in, const int* in_sizes, int n_in,
                              void* d_out, int out_size, void* d_ws, size_t ws_size,
                              hipStream_t stream) {
  const float* in_feat = (const float*)d_in[0];
  const int* src = (const int*)d_in[1];
  const int* dst = (const int*)d_in[2];
  const int* gid = (const int*)d_in[3];
  const float* W1 = (const float*)d_in[4];
  const float* b1 = (const float*)d_in[5];
  const float* W2 = (const float*)d_in[6];
  const float* b2 = (const float*)d_in[7];
  const float* W3 = (const float*)d_in[8];
  const float* b3 = (const float*)d_in[9];
  const float* Wd = (const float*)d_in[10];
  const float* bd = (const float*)d_in[11];
  float* out = (float*)d_out;

  char* ws = (char*)d_ws;
  size_t o = 0;
  auto alloc = [&](size_t bytes) -> char* {
    char* p = ws + o;
    o = (o + bytes + 1023) & ~(size_t)1023;
    return p;
  };
  float* hg = (float*)alloc(NG * 64 * 4);
  size_t zero_bytes = o;  // only hg needs zero-init
  int* deg_in = (int*)alloc(NN * 4);
  float* norm_src = (float*)alloc(NN * 4);
  float* norm_dst = (float*)alloc(NN * 4);
  int* row_off = (int*)alloc((NN + 1) * 4);
  int* bsums = (int*)alloc(512);
  ushort* Wt1 = (ushort*)alloc(64 * 128 * 2);
  ushort* Wt2 = (ushort*)alloc(128 * 64 * 2);
  ushort* Wt3 = (ushort*)alloc(64 * 128 * 2);
  int* csr = (int*)alloc((size_t)NE * 4);
  ushort* tbuf = (ushort*)alloc((size_t)NN * 64 * 2);  // bf16 t1, then t3
  ushort* h1s = (ushort*)alloc((size_t)NN * 64 * 2);   // bf16
  ushort* m2 = (ushort*)alloc((size_t)NN * 64 * 2);    // bf16
  (void)ws_size;

  // overlays on [tbuf..) (38.4MB contiguous): all CSR-build scratch is dead
  // before gemm1 (tbuf), agg1 (h1s), agg2 (m2) first write.
  char* ov = (char*)tbuf;
  uint* pdst = (uint*)ov;                                 // 2.45MB
  uint* psrc = (uint*)(ov + 2457600);                     // 2.45MB
  unsigned char* Pb = (unsigned char*)(ov + 4915200);     // 4.9MB
  unsigned char* lrank = (unsigned char*)(ov + 9830400);  // 3.2MB

  hipMemsetAsync(d_ws, 0, zero_bytes, stream);

  const int egrid = (NE + 255) / 256;      // 12500
  const int ngrid = (NN + 255) / 256;      // 391
  const int sgrid = (NN + 1023) / 1024;    // 98
  const int wgrid2 = NN / 8;               // 12500 (pair-gather)
  const int rgrid = (WORDS4 + 255) / 256;  // 49
  const int ggrid = (NN + 63) / 64;        // 1563

  transw_kernel<<<96, 256, 0, stream>>>(W1, W2, W3, Wt1, Wt2, Wt3);
  hist_kernel<<<dim3(NCHUNK, 2), 1024, 0, stream>>>(src, dst, pdst, psrc, lrank);
  reduce2_kernel<<<dim3(rgrid, 2), 256, 0, stream>>>(pdst, psrc, Pb, deg_in,
                                                     norm_dst, norm_src);
  scan1_kernel<<<sgrid, 256, 0, stream>>>(deg_in, row_off, bsums, NN);
  scan2_kernel<<<1, 128, 0, stream>>>(bsums, sgrid, row_off, NN);
  scan3_kernel<<<ngrid, 256, 0, stream>>>(row_off, bsums, NN);
  fill_kernel<<<egrid, 256, 0, stream>>>(src, dst, row_off, Pb, lrank, csr, NE);

  // layer 1: t1 = bf16((in_feat @ W1) * ns)   [MFMA]
  gemm1_kernel<<<ggrid, 256, 0, stream>>>(in_feat, Wt1, norm_src, tbuf, NN);
  // h1s = bf16(relu(seg(t1)*nd + b1) * ns)
  agg1_kernel<<<wgrid2, 256, 0, stream>>>(row_off, csr, tbuf, norm_dst,
                                          norm_src, b1, h1s, NN);
  // m2 = bf16(seg(h1s)*nd)
  agg2_kernel<<<wgrid2, 256, 0, stream>>>(row_off, csr, h1s, norm_dst, m2, NN);
  // t3 = bf16((relu(m2@W2+b2)*ns) @ W3)   [fused MFMA x2]
  gemm23_kernel<<<ggrid, 256, 0, stream>>>(m2, Wt2, b2, norm_src, Wt3, tbuf, NN);
  // hg[g] += relu(seg(t3)*nd + b3)
  agg3_kernel<<<NN / 16, 512, 0, stream>>>(row_off, csr, tbuf, norm_dst, b3,
                                           gid, hg, NN);
  readout_kernel<<<1, 640, 0, stream>>>(hg, Wd, bd, out);
}

// Round 11
// 447.698 us; speedup vs baseline: 2.5985x; 1.0224x over previous
//
#include <hip/hip_runtime.h>
#include <hip/hip_bf16.h>

// GCN: 3x GraphConv(norm='both') + graph readout + dense head.
// Strategy:
//  - ATOMIC-FREE CSR build (R2: device atomics cap ~26G/s):
//      hist (4-bit packed full-range LDS bins, CBITS=16) -> reduce2 (nibble
//      sums + fused norms + hg zero) -> scan1(+transw) -> scan23 -> fill.
//  - Algebra: transform-first for 128->64 layers so ALL gathers are 64-feat.
//  - bf16 features; 8 lanes/edge uint4 loads (R3); ALL dense multiplies are
//    MFMA 16x16x32 bf16 (R4); gemm2+gemm3 fused via LDS tile (R6).
//  - R5: PAIR-GATHER: one wave = 2 adjacent dst nodes over their combined
//    contiguous csr range; j-groups of 8 edges routed to acc0/acc1 by
//    wave-uniform boundary. MEASURED optimum: 1/2/4 nodes per wave =
//    83/73/112 us per agg (R3/R6/R9); quad loses to routing VALU + occupancy,
//    and runtime-indexed private acc arrays scratch-demote (R8: 465MB writes).
//  - R11: dispatch-count trim 14->11 (transw folded into scan1, scan2 merged
//    into scan23, hg zeroed in reduce2, memset dropped) — the agg/gather and
//    CSR-build hot paths are at their measured floors.
//  - agg3: block LDS-reduce 16 nodes -> ~1 atomic row/block.

constexpr int NN = 100000;   // nodes
constexpr int NE = 3200000;  // edges
constexpr int NG = 64;       // graphs

constexpr int CBITS = 16;
constexpr int CHUNK = 1 << CBITS;                 // 65536 edges/chunk
constexpr int NCHUNK = (NE + CHUNK - 1) / CHUNK;  // 49
constexpr int WORDS4 = NN / 8;                    // 12500 packed u4x8 words

typedef __attribute__((ext_vector_type(8))) short short8;
typedef __attribute__((ext_vector_type(4))) float f32x4;
typedef __attribute__((ext_vector_type(2))) float f32x2;

// ---------------- chunked LDS histogram (4-bit bins, full node range) -----
// Per-chunk-per-node counts <=15 (Poisson(0.65); overflow P ~ 1e-9). y picks
// dst (also records local rank from the LDS-atomic return) or src.

__global__ __launch_bounds__(1024) void hist_kernel(
    const int* __restrict__ src, const int* __restrict__ dst,
    uint* __restrict__ pdst, uint* __restrict__ psrc,
    unsigned char* __restrict__ lrank) {
  __shared__ uint bins[WORDS4];  // 50KB
  for (int i = threadIdx.x; i < WORDS4; i += 1024) bins[i] = 0;
  __syncthreads();
  const int c = blockIdx.x;
  const int start = c << CBITS;
  const int end = min(start + CHUNK, NE);
  if (blockIdx.y == 0) {
    for (int i = start + threadIdx.x; i < end; i += 1024) {
      int n = dst[i];
      uint old = atomicAdd(&bins[n >> 3], 1u << ((n & 7) * 4));
      lrank[i] = (unsigned char)((old >> ((n & 7) * 4)) & 0xf);
    }
  } else {
    for (int i = start + threadIdx.x; i < end; i += 1024) {
      int n = src[i];
      atomicAdd(&bins[n >> 3], 1u << ((n & 7) * 4));
    }
  }
  __syncthreads();
  uint* pp = ((blockIdx.y == 0) ? pdst : psrc) + (size_t)c * WORDS4;
  for (int i = threadIdx.x; i < WORDS4; i += 1024) pp[i] = bins[i];
}

// ------- reduce2: nibble sums -> deg_in + chunk-exclusive prefix + norms ---
// y==0: pdst -> (P bytes, deg_in, nd);  y==1: psrc -> ns (+ zero hg).

__global__ __launch_bounds__(256) void reduce2_kernel(
    const uint* __restrict__ pdst, const uint* __restrict__ psrc,
    unsigned char* __restrict__ Pb, int* __restrict__ deg_in,
    float* __restrict__ nd, float* __restrict__ ns, float* __restrict__ hg) {
  int w = blockIdx.x * 256 + threadIdx.x;
  uint run[8] = {0, 0, 0, 0, 0, 0, 0, 0};
  if (blockIdx.y == 0) {
    if (w >= WORDS4) return;
#pragma unroll 7
    for (int c = 0; c < NCHUNK; ++c) {
      uint lo = run[0] | (run[1] << 8) | (run[2] << 16) | (run[3] << 24);
      uint hi = run[4] | (run[5] << 8) | (run[6] << 16) | (run[7] << 24);
      ((uint2*)(Pb + (size_t)c * NN))[w] = make_uint2(lo, hi);
      uint v = pdst[(size_t)c * WORDS4 + w];
#pragma unroll
      for (int k = 0; k < 8; ++k) run[k] += (v >> (4 * k)) & 0xfu;
    }
    ((int4*)deg_in)[2 * w] = make_int4(run[0], run[1], run[2], run[3]);
    ((int4*)deg_in)[2 * w + 1] = make_int4(run[4], run[5], run[6], run[7]);
    float4 f0, f1;
    f0.x = rsqrtf(fmaxf((float)run[0], 1.f));
    f0.y = rsqrtf(fmaxf((float)run[1], 1.f));
    f0.z = rsqrtf(fmaxf((float)run[2], 1.f));
    f0.w = rsqrtf(fmaxf((float)run[3], 1.f));
    f1.x = rsqrtf(fmaxf((float)run[4], 1.f));
    f1.y = rsqrtf(fmaxf((float)run[5], 1.f));
    f1.z = rsqrtf(fmaxf((float)run[6], 1.f));
    f1.w = rsqrtf(fmaxf((float)run[7], 1.f));
    ((float4*)nd)[2 * w] = f0;
    ((float4*)nd)[2 * w + 1] = f1;
  } else {
    if (blockIdx.x == 0) {  // zero hg (64x64 floats = 1024 float4)
      for (int k = threadIdx.x; k < 1024; k += 256)
        ((float4*)hg)[k] = make_float4(0.f, 0.f, 0.f, 0.f);
    }
    if (w >= WORDS4) return;
#pragma unroll 7
    for (int c = 0; c < NCHUNK; ++c) {
      uint v = psrc[(size_t)c * WORDS4 + w];
#pragma unroll
      for (int k = 0; k < 8; ++k) run[k] += (v >> (4 * k)) & 0xfu;
    }
    float4 f0, f1;
    f0.x = rsqrtf(fmaxf((float)run[0], 1.f));
    f0.y = rsqrtf(fmaxf((float)run[1], 1.f));
    f0.z = rsqrtf(fmaxf((float)run[2], 1.f));
    f0.w = rsqrtf(fmaxf((float)run[3], 1.f));
    f1.x = rsqrtf(fmaxf((float)run[4], 1.f));
    f1.y = rsqrtf(fmaxf((float)run[5], 1.f));
    f1.z = rsqrtf(fmaxf((float)run[6], 1.f));
    f1.w = rsqrtf(fmaxf((float)run[7], 1.f));
    ((float4*)ns)[2 * w] = f0;
    ((float4*)ns)[2 * w + 1] = f1;
  }
}

// ---------------- bf16 helpers ----------------

__device__ __forceinline__ uint pack_bf16(float a, float b) {
  uint ua = __float_as_uint(a), ub = __float_as_uint(b);
  ua = (ua + 0x7fffu + ((ua >> 16) & 1u)) >> 16;          // RNE
  ub = (ub + 0x7fffu + ((ub >> 16) & 1u)) & 0xffff0000u;  // RNE
  return ua | ub;  // a -> low ushort (even idx), b -> high (odd idx)
}

__device__ __forceinline__ ushort to_bf16(float a) {
  uint ua = __float_as_uint(a);
  return (ushort)((ua + 0x7fffu + ((ua >> 16) & 1u)) >> 16);
}

union U16 {
  uint4 u;
  short8 s;
};
__device__ __forceinline__ short8 as_short8(uint4 u) {
  U16 t;
  t.u = u;
  return t.s;
}

__device__ __forceinline__ f32x2 bf2(uint u) {
  f32x2 r;
  r.x = __uint_as_float(u << 16);
  r.y = __uint_as_float(u & 0xffff0000u);
  return r;
}

__device__ __forceinline__ void add8(f32x2* a, uint4 v) {
  a[0] += bf2(v.x);
  a[1] += bf2(v.y);
  a[2] += bf2(v.z);
  a[3] += bf2(v.w);
}

// -------- scan1 + fused weight transpose (saves a dispatch) --------------
// scan part: exclusive scan of deg over 1024-elem tiles; transw part:
// Wt1[n][k]=W1[k][n] etc., spread over the first 24576 global threads.

__global__ __launch_bounds__(256) void scan1t_kernel(
    const int* __restrict__ deg, int* __restrict__ row_off,
    int* __restrict__ bsums, int n, const float* __restrict__ W1,
    const float* __restrict__ W2, const float* __restrict__ W3,
    ushort* __restrict__ Wt1, ushort* __restrict__ Wt2,
    ushort* __restrict__ Wt3) {
  int gi = blockIdx.x * 256 + threadIdx.x;
  if (gi < 8192) {
    int nn = gi >> 7, k = gi & 127;
    Wt1[gi] = to_bf16(W1[k * 64 + nn]);
  } else if (gi < 16384) {
    int j = gi - 8192;
    int nn = j >> 6, k = j & 63;
    Wt2[j] = to_bf16(W2[k * 128 + nn]);
  } else if (gi < 24576) {
    int j = gi - 16384;
    int nn = j >> 7, k = j & 127;
    Wt3[j] = to_bf16(W3[k * 64 + nn]);
  }
  __shared__ int s[256];
  int t = threadIdx.x;
  int base = blockIdx.x * 1024 + t * 4;
  int v0 = 0, v1 = 0, v2 = 0, v3 = 0;
  if (base + 0 < n) v0 = deg[base + 0];
  if (base + 1 < n) v1 = deg[base + 1];
  if (base + 2 < n) v2 = deg[base + 2];
  if (base + 3 < n) v3 = deg[base + 3];
  int sum = v0 + v1 + v2 + v3;
  s[t] = sum;
  __syncthreads();
  for (int off = 1; off < 256; off <<= 1) {
    int x = (t >= off) ? s[t - off] : 0;
    __syncthreads();
    s[t] += x;
    __syncthreads();
  }
  int excl = s[t] - sum;
  if (t == 255) bsums[blockIdx.x] = s[255];
  if (base + 0 < n) row_off[base + 0] = excl;
  if (base + 1 < n) row_off[base + 1] = excl + v0;
  if (base + 2 < n) row_off[base + 2] = excl + v0 + v1;
  if (base + 3 < n) row_off[base + 3] = excl + v0 + v1 + v2;
}

// -------- scan23: each block redundantly scans the <=128 block sums in LDS
// (512B), then adds the exclusive prefix to its 256 row_off entries. Block 0
// also writes row_off[n] = grand total. Replaces scan2+scan3 (one dispatch).

__global__ __launch_bounds__(256) void scan23_kernel(
    int* __restrict__ row_off, const int* __restrict__ bsums, int nb, int n) {
  __shared__ int si[128], so[128];
  int t = threadIdx.x;
  if (t < 128) {
    int v = (t < nb) ? bsums[t] : 0;
    si[t] = v;
    so[t] = v;
  }
  __syncthreads();
  for (int off = 1; off < 128; off <<= 1) {
    int x = 0;
    if (t < 128 && t >= off) x = si[t - off];
    __syncthreads();
    if (t < 128) si[t] += x;
    __syncthreads();
  }
  int i = blockIdx.x * 256 + t;
  if (i < n) {
    int bk = i >> 10;
    row_off[i] += si[bk] - so[bk];  // exclusive prefix of block bk
  }
  if (blockIdx.x == 0 && t == 0) row_off[n] = si[127];
}

// ---------------- CSR fill (atomic-free) ----------------

__global__ __launch_bounds__(256) void fill_kernel(
    const int* __restrict__ src, const int* __restrict__ dst,
    const int* __restrict__ row_off, const unsigned char* __restrict__ Pb,
    const unsigned char* __restrict__ lrank, int* __restrict__ csr, int e) {
  int i = blockIdx.x * 256 + threadIdx.x;
  if (i < e) {
    int d = dst[i];
    int c = i >> CBITS;
    int pos = row_off[d] + (int)Pb[(size_t)c * NN + d] + (int)lrank[i];
    csr[pos] = src[i];
  }
}

// ---------------- skinny MFMA GEMM (layer 1): t1 = bf16((A@W1)*ns) --------
// A: [n][128] fp32 (inline bf16 convert), Wt: [64][128] bf16, C: [n][64].
// mfma_f32_16x16x32_bf16: A-frag A[m=lane&15][k=quad*8+j], C/D col=lane&15,
// row=quad*4+reg  [learn_hip m89 verified].

__global__ __launch_bounds__(256) void gemm1_kernel(
    const float* __restrict__ A, const ushort* __restrict__ Wt,
    const float* __restrict__ scale, ushort* __restrict__ C, int n) {
  int wid = threadIdx.x >> 6, lane = threadIdx.x & 63;
  int r = lane & 15, quad = lane >> 4;
  int m16 = blockIdx.x * 64 + wid * 16;
  if (m16 >= n) return;
  int mc = min(m16 + r, n - 1);
  short8 a[4];
#pragma unroll
  for (int ks = 0; ks < 4; ++ks) {
    const float4* p = (const float4*)(A + (size_t)mc * 128 + ks * 32 + quad * 8);
    float4 x = p[0], y = p[1];
    uint4 u;
    u.x = pack_bf16(x.x, x.y);
    u.y = pack_bf16(x.z, x.w);
    u.z = pack_bf16(y.x, y.y);
    u.w = pack_bf16(y.z, y.w);
    a[ks] = as_short8(u);
  }
#pragma unroll
  for (int nt = 0; nt < 4; ++nt) {
    f32x4 acc = {0.f, 0.f, 0.f, 0.f};
#pragma unroll
    for (int ks = 0; ks < 4; ++ks) {
      short8 b = as_short8(
          *(const uint4*)(Wt + (size_t)(nt * 16 + r) * 128 + ks * 32 + quad * 8));
      acc = __builtin_amdgcn_mfma_f32_16x16x32_bf16(a[ks], b, acc, 0, 0, 0);
    }
#pragma unroll
    for (int reg = 0; reg < 4; ++reg) {
      int m = m16 + quad * 4 + reg;
      if (m < n) C[(size_t)m * 64 + nt * 16 + r] = to_bf16(acc[reg] * scale[m]);
    }
  }
}

// ------- fused layers 2+3 dense: t3 = (relu(m2@W2+b2)*ns) @ W3 ------------
// First MFMA (K=64,N=128) -> epilogue -> bf16 tile in LDS (padded 136) ->
// A-frags for second MFMA (K=128,N=64). Same-wave LDS write->read only.

__global__ __launch_bounds__(256) void gemm23_kernel(
    const ushort* __restrict__ m2, const ushort* __restrict__ Wt2,
    const float* __restrict__ b2, const float* __restrict__ ns,
    const ushort* __restrict__ Wt3, ushort* __restrict__ t3, int n) {
  __shared__ ushort sX[4][16][136];  // 17.4KB, pad keeps 16B align
  int wid = threadIdx.x >> 6, lane = threadIdx.x & 63;
  int r = lane & 15, quad = lane >> 4;
  int m16 = blockIdx.x * 64 + wid * 16;
  if (m16 >= n) return;
  int mc = min(m16 + r, n - 1);
  short8 a1[2];
#pragma unroll
  for (int ks = 0; ks < 2; ++ks)
    a1[ks] = as_short8(*(const uint4*)(m2 + (size_t)mc * 64 + ks * 32 + quad * 8));
  float nsv[4];
#pragma unroll
  for (int reg = 0; reg < 4; ++reg)
    nsv[reg] = ns[min(m16 + quad * 4 + reg, n - 1)];
#pragma unroll
  for (int nt = 0; nt < 8; ++nt) {
    f32x4 acc = {0.f, 0.f, 0.f, 0.f};
#pragma unroll
    for (int ks = 0; ks < 2; ++ks) {
      short8 b = as_short8(
          *(const uint4*)(Wt2 + (size_t)(nt * 16 + r) * 64 + ks * 32 + quad * 8));
      acc = __builtin_amdgcn_mfma_f32_16x16x32_bf16(a1[ks], b, acc, 0, 0, 0);
    }
    float bv = b2[nt * 16 + r];
#pragma unroll
    for (int reg = 0; reg < 4; ++reg) {
      float v = fmaxf(acc[reg] + bv, 0.f) * nsv[reg];
      sX[wid][quad * 4 + reg][nt * 16 + r] = to_bf16(v);
    }
  }
  short8 a2[4];
#pragma unroll
  for (int ks = 0; ks < 4; ++ks)
    a2[ks] = as_short8(*(const uint4*)(&sX[wid][r][ks * 32 + quad * 8]));
#pragma unroll
  for (int nt = 0; nt < 4; ++nt) {
    f32x4 acc = {0.f, 0.f, 0.f, 0.f};
#pragma unroll
    for (int ks = 0; ks < 4; ++ks) {
      short8 b = as_short8(
          *(const uint4*)(Wt3 + (size_t)(nt * 16 + r) * 128 + ks * 32 + quad * 8));
      acc = __builtin_amdgcn_mfma_f32_16x16x32_bf16(a2[ks], b, acc, 0, 0, 0);
    }
#pragma unroll
    for (int reg = 0; reg < 4; ++reg) {
      int m = m16 + quad * 4 + reg;
      if (m < n) t3[(size_t)m * 64 + nt * 16 + r] = to_bf16(acc[reg]);
    }
  }
}

// ---------------- paired 64-feature bf16 CSR gather ----------------
// One wave gathers TWO adjacent dst rows over the combined contiguous csr
// range [rs, re), boundary rm. 8 lanes/edge, uint4 = 8 bf16 features/lane.
// j-groups of 8 edges route to acc0/acc1 by the wave-uniform boundary
// c0 = rm - e0; only the straddling group pays a mask split. Butterfly at
// the end leaves every lane with both nodes' 8-feature totals.

__device__ __forceinline__ void gather2_bf16(const int* __restrict__ csr,
                                             const ushort* __restrict__ x,
                                             int rs, int rm, int re, int lane,
                                             f32x2* a0, f32x2* a1) {
  const int eg = lane >> 3;
  const int fl = lane & 7;
  for (int e0 = rs; e0 < re; e0 += 64) {
    int idx = e0 + lane;
    int sv = (idx < re) ? csr[idx] : 0;
    int cnt = re - e0;
    if (cnt > 64) cnt = 64;
    int c0 = rm - e0;  // slots < c0 belong to node0
#pragma unroll
    for (int j = 0; j < 8; ++j) {
      int jb = j * 8;
      if (jb < cnt) {  // wave-uniform
        int s = __shfl(sv, jb + eg);
        uint4 v = *(const uint4*)(x + (size_t)s * 64 + fl * 8);
        if (jb + 8 > cnt) {  // partial tail: mask invalid edge-groups
          uint mv = ((jb + eg) < cnt) ? 0xffffffffu : 0u;
          v.x &= mv; v.y &= mv; v.z &= mv; v.w &= mv;
        }
        if (jb + 8 <= c0) {
          add8(a0, v);
        } else if (jb >= c0) {
          add8(a1, v);
        } else {  // straddles the node boundary
          uint m0 = ((jb + eg) < c0) ? 0xffffffffu : 0u;
          uint4 v0;
          v0.x = v.x & m0; v0.y = v.y & m0; v0.z = v.z & m0; v0.w = v.w & m0;
          add8(a0, v0);
          v.x ^= v0.x; v.y ^= v0.y; v.z ^= v0.z; v.w ^= v0.w;
          add8(a1, v);
        }
      }
    }
  }
#pragma unroll
  for (int k = 0; k < 4; ++k) {
    a0[k].x += __shfl_xor(a0[k].x, 8);
    a0[k].x += __shfl_xor(a0[k].x, 16);
    a0[k].x += __shfl_xor(a0[k].x, 32);
    a0[k].y += __shfl_xor(a0[k].y, 8);
    a0[k].y += __shfl_xor(a0[k].y, 16);
    a0[k].y += __shfl_xor(a0[k].y, 32);
    a1[k].x += __shfl_xor(a1[k].x, 8);
    a1[k].x += __shfl_xor(a1[k].x, 16);
    a1[k].x += __shfl_xor(a1[k].x, 32);
    a1[k].y += __shfl_xor(a1[k].y, 8);
    a1[k].y += __shfl_xor(a1[k].y, 16);
    a1[k].y += __shfl_xor(a1[k].y, 32);
  }
}

// select feature k (0..7) of the proper node's accumulator
#define ACC_SEL(k) ((eg == 0) ? a0[(k) >> 1][(k)&1] : a1[(k) >> 1][(k)&1])

// ---------------- layer 1 aggregate + epilogue (bf16 out) ----------------
// h1s[n][j] = bf16(relu(seg(t1)*nd + b1[j]) * ns[n]); 2 nodes/wave.

__global__ __launch_bounds__(256) void agg1_kernel(
    const int* __restrict__ row_off, const int* __restrict__ csr,
    const ushort* __restrict__ t, const float* __restrict__ nd,
    const float* __restrict__ ns, const float* __restrict__ b,
    ushort* __restrict__ out, int n) {
  int wid = threadIdx.x >> 6, lane = threadIdx.x & 63;
  int n0 = blockIdx.x * 8 + wid * 2;  // n % 8 == 0
  int rs = row_off[n0], rm = row_off[n0 + 1], re = row_off[n0 + 2];
  f32x2 a0[4] = {{0, 0}, {0, 0}, {0, 0}, {0, 0}};
  f32x2 a1[4] = {{0, 0}, {0, 0}, {0, 0}, {0, 0}};
  gather2_bf16(csr, t, rs, rm, re, lane, a0, a1);
  int eg = lane >> 3, fl = lane & 7;
  if (eg < 2) {  // eg==0 -> node0, eg==1 -> node1
    int node = n0 + eg;
    float ndv = nd[node], nsv = ns[node];
    const float4* bp = (const float4*)(b + fl * 8);
    float4 b0 = bp[0], b1v = bp[1];
    float o0 = fmaxf(ACC_SEL(0) * ndv + b0.x, 0.f) * nsv;
    float o1 = fmaxf(ACC_SEL(1) * ndv + b0.y, 0.f) * nsv;
    float o2 = fmaxf(ACC_SEL(2) * ndv + b0.z, 0.f) * nsv;
    float o3 = fmaxf(ACC_SEL(3) * ndv + b0.w, 0.f) * nsv;
    float o4 = fmaxf(ACC_SEL(4) * ndv + b1v.x, 0.f) * nsv;
    float o5 = fmaxf(ACC_SEL(5) * ndv + b1v.y, 0.f) * nsv;
    float o6 = fmaxf(ACC_SEL(6) * ndv + b1v.z, 0.f) * nsv;
    float o7 = fmaxf(ACC_SEL(7) * ndv + b1v.w, 0.f) * nsv;
    uint4 v;
    v.x = pack_bf16(o0, o1);
    v.y = pack_bf16(o2, o3);
    v.z = pack_bf16(o4, o5);
    v.w = pack_bf16(o6, o7);
    *(uint4*)(out + (size_t)node * 64 + fl * 8) = v;
  }
}

// ---------------- layer 2 aggregate (gather-only, bf16 out) ----------------
// m2[n][j] = bf16(seg(h1s)*nd); 2 nodes/wave.

__global__ __launch_bounds__(256) void agg2_kernel(
    const int* __restrict__ row_off, const int* __restrict__ csr,
    const ushort* __restrict__ h1s, const float* __restrict__ nd,
    ushort* __restrict__ m2, int n) {
  int wid = threadIdx.x >> 6, lane = threadIdx.x & 63;
  int n0 = blockIdx.x * 8 + wid * 2;
  int rs = row_off[n0], rm = row_off[n0 + 1], re = row_off[n0 + 2];
  f32x2 a0[4] = {{0, 0}, {0, 0}, {0, 0}, {0, 0}};
  f32x2 a1[4] = {{0, 0}, {0, 0}, {0, 0}, {0, 0}};
  gather2_bf16(csr, h1s, rs, rm, re, lane, a0, a1);
  int eg = lane >> 3, fl = lane & 7;
  if (eg < 2) {
    int node = n0 + eg;
    float ndv = nd[node];
    uint4 v;
    v.x = pack_bf16(ACC_SEL(0) * ndv, ACC_SEL(1) * ndv);
    v.y = pack_bf16(ACC_SEL(2) * ndv, ACC_SEL(3) * ndv);
    v.z = pack_bf16(ACC_SEL(4) * ndv, ACC_SEL(5) * ndv);
    v.w = pack_bf16(ACC_SEL(6) * ndv, ACC_SEL(7) * ndv);
    *(uint4*)(m2 + (size_t)node * 64 + fl * 8) = v;
  }
}

// ---------------- layer 3 aggregate + block-reduced readout ----------------
// 512 threads = 8 waves x 2 nodes = 16 nodes/block; LDS tree-reduce ->
// ~1 atomic row per block (gids sorted: nearly all blocks gid-uniform).

__global__ __launch_bounds__(512) void agg3_kernel(
    const int* __restrict__ row_off, const int* __restrict__ csr,
    const ushort* __restrict__ t, const float* __restrict__ nd,
    const float* __restrict__ b, const int* __restrict__ gid,
    float* __restrict__ hg, int n) {
  __shared__ float sO[16][64];
  __shared__ int sG[16];
  __shared__ int uni;
  int wid = threadIdx.x >> 6, lane = threadIdx.x & 63;
  int n0 = blockIdx.x * 16 + wid * 2;  // NN % 16 == 0
  int rs = row_off[n0], rm = row_off[n0 + 1], re = row_off[n0 + 2];
  f32x2 a0[4] = {{0, 0}, {0, 0}, {0, 0}, {0, 0}};
  f32x2 a1[4] = {{0, 0}, {0, 0}, {0, 0}, {0, 0}};
  gather2_bf16(csr, t, rs, rm, re, lane, a0, a1);
  int eg = lane >> 3, fl = lane & 7;
  if (eg < 2) {
    int node = n0 + eg;
    int row = wid * 2 + eg;
    float ndv = nd[node];
    const float4* bp = (const float4*)(b + fl * 8);
    float4 b0 = bp[0], b1v = bp[1];
    sO[row][fl * 8 + 0] = fmaxf(ACC_SEL(0) * ndv + b0.x, 0.f);
    sO[row][fl * 8 + 1] = fmaxf(ACC_SEL(1) * ndv + b0.y, 0.f);
    sO[row][fl * 8 + 2] = fmaxf(ACC_SEL(2) * ndv + b0.z, 0.f);
    sO[row][fl * 8 + 3] = fmaxf(ACC_SEL(3) * ndv + b0.w, 0.f);
    sO[row][fl * 8 + 4] = fmaxf(ACC_SEL(4) * ndv + b1v.x, 0.f);
    sO[row][fl * 8 + 5] = fmaxf(ACC_SEL(5) * ndv + b1v.y, 0.f);
    sO[row][fl * 8 + 6] = fmaxf(ACC_SEL(6) * ndv + b1v.z, 0.f);
    sO[row][fl * 8 + 7] = fmaxf(ACC_SEL(7) * ndv + b1v.w, 0.f);
  }
  if (lane == 0) sG[wid * 2] = gid[n0];
  if (lane == 8) sG[wid * 2 + 1] = gid[n0 + 1];
  __syncthreads();
  if (threadIdx.x == 0) {
    int g0 = sG[0], u = 1;
#pragma unroll
    for (int i = 1; i < 16; ++i) u &= (sG[i] == g0);
    uni = u;
  }
  __syncthreads();
  if (uni) {
    int r = threadIdx.x >> 6;  // 0..7
#pragma unroll
    for (int s = 8; s >= 1; s >>= 1) {
      if (r < s) sO[r][lane] += sO[r + s][lane];
      __syncthreads();
    }
    if (threadIdx.x < 64) atomicAdd(&hg[sG[0] * 64 + lane], sO[0][lane]);
  } else {
    atomicAdd(&hg[sG[wid * 2] * 64 + lane], sO[wid * 2][lane]);
    atomicAdd(&hg[sG[wid * 2 + 1] * 64 + lane], sO[wid * 2 + 1][lane]);
  }
}

// ---------------- readout dense ----------------

__global__ __launch_bounds__(640) void readout_kernel(
    const float* __restrict__ hg, const float* __restrict__ Wd,
    const float* __restrict__ bd, float* __restrict__ out) {
  int t = threadIdx.x;  // 640 = 64 graphs * 10 classes
  int g = t / 10, c = t % 10;
  float o = bd[c];
#pragma unroll 8
  for (int k = 0; k < 64; ++k) o += tanhf(hg[g * 64 + k]) * Wd[k * 10 + c];
  out[t] = o;
}

// ---------------- launch ----------------

extern "C" void kernel_launch(void* const* d_in, const int* in_sizes, int n_in,
                              void* d_out, int out_size, void* d_ws, size_t ws_size,
                              hipStream_t stream) {
  const float* in_feat = (const float*)d_in[0];
  const int* src = (const int*)d_in[1];
  const int* dst = (const int*)d_in[2];
  const int* gid = (const int*)d_in[3];
  const float* W1 = (const float*)d_in[4];
  const float* b1 = (const float*)d_in[5];
  const float* W2 = (const float*)d_in[6];
  const float* b2 = (const float*)d_in[7];
  const float* W3 = (const float*)d_in[8];
  const float* b3 = (const float*)d_in[9];
  const float* Wd = (const float*)d_in[10];
  const float* bd = (const float*)d_in[11];
  float* out = (float*)d_out;

  char* ws = (char*)d_ws;
  size_t o = 0;
  auto alloc = [&](size_t bytes) -> char* {
    char* p = ws + o;
    o = (o + bytes + 1023) & ~(size_t)1023;
    return p;
  };
  float* hg = (float*)alloc(NG * 64 * 4);  // zeroed inside reduce2 (y==1)
  int* deg_in = (int*)alloc(NN * 4);
  float* norm_src = (float*)alloc(NN * 4);
  float* norm_dst = (float*)alloc(NN * 4);
  int* row_off = (int*)alloc((NN + 1) * 4);
  int* bsums = (int*)alloc(512);
  ushort* Wt1 = (ushort*)alloc(64 * 128 * 2);
  ushort* Wt2 = (ushort*)alloc(128 * 64 * 2);
  ushort* Wt3 = (ushort*)alloc(64 * 128 * 2);
  int* csr = (int*)alloc((size_t)NE * 4);
  ushort* tbuf = (ushort*)alloc((size_t)NN * 64 * 2);  // bf16 t1, then t3
  ushort* h1s = (ushort*)alloc((size_t)NN * 64 * 2);   // bf16
  ushort* m2 = (ushort*)alloc((size_t)NN * 64 * 2);    // bf16
  (void)ws_size;

  // overlays on [tbuf..) (38.4MB contiguous): all CSR-build scratch is dead
  // before gemm1 (tbuf), agg1 (h1s), agg2 (m2) first write.
  char* ov = (char*)tbuf;
  uint* pdst = (uint*)ov;                                 // 2.45MB
  uint* psrc = (uint*)(ov + 2457600);                     // 2.45MB
  unsigned char* Pb = (unsigned char*)(ov + 4915200);     // 4.9MB
  unsigned char* lrank = (unsigned char*)(ov + 9830400);  // 3.2MB

  const int egrid = (NE + 255) / 256;      // 12500
  const int ngrid = (NN + 255) / 256;      // 391
  const int sgrid = (NN + 1023) / 1024;    // 98
  const int wgrid2 = NN / 8;               // 12500 (pair-gather)
  const int rgrid = (WORDS4 + 255) / 256;  // 49
  const int ggrid = (NN + 63) / 64;        // 1563

  hist_kernel<<<dim3(NCHUNK, 2), 1024, 0, stream>>>(src, dst, pdst, psrc, lrank);
  reduce2_kernel<<<dim3(rgrid, 2), 256, 0, stream>>>(pdst, psrc, Pb, deg_in,
                                                     norm_dst, norm_src, hg);
  scan1t_kernel<<<sgrid, 256, 0, stream>>>(deg_in, row_off, bsums, NN, W1, W2,
                                           W3, Wt1, Wt2, Wt3);
  scan23_kernel<<<ngrid, 256, 0, stream>>>(row_off, bsums, sgrid, NN);
  fill_kernel<<<egrid, 256, 0, stream>>>(src, dst, row_off, Pb, lrank, csr, NE);

  // layer 1: t1 = bf16((in_feat @ W1) * ns)   [MFMA]
  gemm1_kernel<<<ggrid, 256, 0, stream>>>(in_feat, Wt1, norm_src, tbuf, NN);
  // h1s = bf16(relu(seg(t1)*nd + b1) * ns)
  agg1_kernel<<<wgrid2, 256, 0, stream>>>(row_off, csr, tbuf, norm_dst,
                                          norm_src, b1, h1s, NN);
  // m2 = bf16(seg(h1s)*nd)
  agg2_kernel<<<wgrid2, 256, 0, stream>>>(row_off, csr, h1s, norm_dst, m2, NN);
  // t3 = bf16((relu(m2@W2+b2)*ns) @ W3)   [fused MFMA x2]
  gemm23_kernel<<<ggrid, 256, 0, stream>>>(m2, Wt2, b2, norm_src, Wt3, tbuf, NN);
  // hg[g] += relu(seg(t3)*nd + b3)
  agg3_kernel<<<NN / 16, 512, 0, stream>>>(row_off, csr, tbuf, norm_dst, b3,
                                           gid, hg, NN);
  readout_kernel<<<1, 640, 0, stream>>>(hg, Wd, bd, out);
}